// Round 12
// baseline (917.638 us; speedup 1.0000x reference)
//
#include <hip/hip_runtime.h>
#include <hip/hip_fp16.h>
#include <cstdint>

#define IN_DIM   128
#define HIDC     64
#define HEADS    4
#define OUT_DIM  40
#define NEG_SLOPE 0.2f
#define BN_EPS   1e-5f

typedef unsigned short ushortt;
typedef float fx4 __attribute__((ext_vector_type(4)));

__device__ __forceinline__ float bfval(ushortt u) {
    return __uint_as_float(((unsigned)u) << 16);
}
__device__ __forceinline__ ushortt f2bf(float f) {
    unsigned u = __float_as_uint(f);
    u += 0x7fffu + ((u >> 16) & 1u);
    return (ushortt)(u >> 16);
}
__device__ __forceinline__ unsigned pack2bf(float a, float b) {
    return (unsigned)f2bf(a) | ((unsigned)f2bf(b) << 16);
}

// acc[0..7] += a * bf16x8(h)
__device__ __forceinline__ void acc8(float* acc, float a, uint4 h) {
    unsigned u;
    u = h.x;
    acc[0] = fmaf(a, __uint_as_float(u << 16), acc[0]);
    acc[1] = fmaf(a, __uint_as_float(u & 0xffff0000u), acc[1]);
    u = h.y;
    acc[2] = fmaf(a, __uint_as_float(u << 16), acc[2]);
    acc[3] = fmaf(a, __uint_as_float(u & 0xffff0000u), acc[3]);
    u = h.z;
    acc[4] = fmaf(a, __uint_as_float(u << 16), acc[4]);
    acc[5] = fmaf(a, __uint_as_float(u & 0xffff0000u), acc[5]);
    u = h.w;
    acc[6] = fmaf(a, __uint_as_float(u << 16), acc[6]);
    acc[7] = fmaf(a, __uint_as_float(u & 0xffff0000u), acc[7]);
}

// ---------------- CSR build ----------------
__global__ void detect_kernel(const unsigned int* __restrict__ e, int* __restrict__ flag) {
    __shared__ int any;
    if (threadIdx.x == 0) any = 0;
    __syncthreads();
    for (int i = threadIdx.x; i < 1024; i += 256)
        if (e[2 * i + 1] != 0u) any = 1;
    __syncthreads();
    if (threadIdx.x == 0) flag[0] = any ? 0 : 1;   // 1 => int64
}

__device__ __forceinline__ int load_idx(const int* ei, int is64, long long pos) {
    return is64 ? ei[2 * pos] : ei[pos];
}

__global__ void hist_kernel(const int* __restrict__ ei, const int* __restrict__ flag,
                            int* __restrict__ deg, int E, int Etot) {
    int i = blockIdx.x * 256 + threadIdx.x;
    if (i >= Etot) return;
    int is64 = flag[0];
    int dst = (i < E) ? load_idx(ei, is64, (long long)E + i) : (i - E);
    atomicAdd(&deg[dst], 1);
}

__global__ void scan_kernel(int* __restrict__ data, int n) {
    __shared__ int wsum[16];
    __shared__ int chunk_total;
    int lane = threadIdx.x & 63;
    int w = threadIdx.x >> 6;
    int carry = 0;
    for (int base = 0; base < n; base += 1024) {
        int i = base + (int)threadIdx.x;
        int v = (i < n) ? data[i] : 0;
        int x = v;
        #pragma unroll
        for (int ofs = 1; ofs < 64; ofs <<= 1) {
            int y = __shfl_up(x, ofs);
            if (lane >= ofs) x += y;
        }
        if (lane == 63) wsum[w] = x;
        __syncthreads();
        if (w == 0) {
            int s = (lane < 16) ? wsum[lane] : 0;
            #pragma unroll
            for (int ofs = 1; ofs < 16; ofs <<= 1) {
                int y = __shfl_up(s, ofs);
                if (lane >= ofs) s += y;
            }
            if (lane < 16) wsum[lane] = s;
            if (lane == 15) chunk_total = s;
        }
        __syncthreads();
        int woff = (w > 0) ? wsum[w - 1] : 0;
        if (i < n) data[i] = (x + woff) - v + carry;
        int ct = chunk_total;
        __syncthreads();
        carry += ct;
    }
}

__global__ void scatter_kernel(const int* __restrict__ ei, const int* __restrict__ flag,
                               int* __restrict__ cursor, int* __restrict__ csr,
                               int* __restrict__ dstv, int E, int Etot) {
    int i = blockIdx.x * 256 + threadIdx.x;
    if (i >= Etot) return;
    int is64 = flag[0];
    int src, dst;
    if (i < E) {
        src = load_idx(ei, is64, i);
        dst = load_idx(ei, is64, (long long)E + i);
    } else {
        src = dst = i - E;
    }
    int pos = atomicAdd(&cursor[dst], 1);
    csr[pos] = src;
    dstv[pos] = dst;
}

// ---------------- fold bias+BN into scale/shift ----------------
__global__ void prep_bn_kernel(const float* b1, const float* g1, const float* bb1,
                               const float* m1, const float* v1,
                               const float* b2, const float* g2, const float* bb2,
                               const float* m2, const float* v2,
                               float* __restrict__ bnsc, float* __restrict__ bnsh) {
    int t = threadIdx.x;
    if (t < 256) {
        float s = g1[t] * rsqrtf(v1[t] + BN_EPS);
        bnsc[t] = s;
        bnsh[t] = (b1[t] - m1[t]) * s + bb1[t];
    } else if (t < 320) {
        int c = t - 256;
        float s = g2[c] * rsqrtf(v2[c] + BN_EPS);
        bnsc[t] = s;
        bnsh[t] = (b2[c] - m2[c]) * s + bb2[c];
    }
}

// ---------------- register-tiled GEMM + fused attention dots -> bf16 h ----------------
// L1MODE: h stored HEAD-MAJOR [head][node][64]; a_s4/a_d4 node-major [node*4+head].
// else:   h row-major [node][64]; a_s[node], a_d[node].
template <int K, int BN, int TN, int NC, int LDW, bool ABF16, bool L1MODE>
__launch_bounds__(256)
__global__ void gemm_fused_kernel(const void* __restrict__ Av, const float* __restrict__ W,
                                  ushortt* __restrict__ hB,
                                  const float* __restrict__ atts, const float* __restrict__ attd,
                                  float* __restrict__ a_s, float* __restrict__ a_d,
                                  int M, int Nn) {
    __shared__ float Al[8][128];
    __shared__ float Wl[8][BN];
    int m0 = blockIdx.x * 128;
    int n0 = blockIdx.y * BN;
    int t = threadIdx.x;
    int tm = t >> 4, tn = t & 15;
    float acc[8][TN] = {};
    int r = t >> 1, kq = (t & 1) * 4;

    for (int k0 = 0; k0 < K; k0 += 8) {
        if constexpr (ABF16) {
            const ushortt* A = (const ushortt*)Av;
            uint2 av = make_uint2(0u, 0u);
            if (m0 + r < M) av = *(const uint2*)(A + (size_t)(m0 + r) * K + k0 + kq);
            Al[kq + 0][r] = bfval((ushortt)(av.x & 0xffffu));
            Al[kq + 1][r] = bfval((ushortt)(av.x >> 16));
            Al[kq + 2][r] = bfval((ushortt)(av.y & 0xffffu));
            Al[kq + 3][r] = bfval((ushortt)(av.y >> 16));
        } else {
            const float* A = (const float*)Av;
            float4 av = make_float4(0.f, 0.f, 0.f, 0.f);
            if (m0 + r < M) av = *(const float4*)&A[(size_t)(m0 + r) * K + k0 + kq];
            Al[kq + 0][r] = av.x; Al[kq + 1][r] = av.y;
            Al[kq + 2][r] = av.z; Al[kq + 3][r] = av.w;
        }
        if constexpr (BN == 128) {
            int kk = t >> 5, c4 = (t & 31) * 4;
            *(float4*)&Wl[kk][c4] = *(const float4*)&W[(size_t)(k0 + kk) * LDW + n0 + c4];
        } else {
            int kk = t >> 5, c2 = (t & 31) * 2;
            float2 wv = make_float2(0.f, 0.f);
            if (c2 + 2 <= NC) wv = *(const float2*)&W[(size_t)(k0 + kk) * LDW + n0 + c2];
            *(float2*)&Wl[kk][c2] = wv;
        }
        __syncthreads();
        #pragma unroll
        for (int k = 0; k < 8; ++k) {
            float4 a0 = *(const float4*)&Al[k][tm * 8];
            float4 a1 = *(const float4*)&Al[k][tm * 8 + 4];
            float aa[8] = {a0.x, a0.y, a0.z, a0.w, a1.x, a1.y, a1.z, a1.w};
            if constexpr (TN == 8) {
                float4 w0 = *(const float4*)&Wl[k][tn * 4];
                float4 w1 = *(const float4*)&Wl[k][64 + tn * 4];
                float ww[8] = {w0.x, w0.y, w0.z, w0.w, w1.x, w1.y, w1.z, w1.w};
                #pragma unroll
                for (int i = 0; i < 8; ++i)
                    #pragma unroll
                    for (int j = 0; j < 8; ++j)
                        acc[i][j] = fmaf(aa[i], ww[j], acc[i][j]);
            } else {
                float4 w0 = *(const float4*)&Wl[k][tn * 4];
                float ww[4] = {w0.x, w0.y, w0.z, w0.w};
                #pragma unroll
                for (int i = 0; i < 8; ++i)
                    #pragma unroll
                    for (int j = 0; j < 4; ++j)
                        acc[i][j] = fmaf(aa[i], ww[j], acc[i][j]);
            }
        }
        __syncthreads();
    }
    // ---- epilogue: bf16 stores + fused per-row attention dots ----
    #pragma unroll
    for (int i = 0; i < 8; ++i) {
        int m = m0 + tm * 8 + i;
        bool valid = m < M;
        if constexpr (L1MODE) {
            int h0 = n0 >> 6;
            if (valid) {
                ushortt* r0 = hB + ((size_t)h0 * Nn + m) * 64 + tn * 4;
                *(uint2*)r0 = make_uint2(pack2bf(acc[i][0], acc[i][1]),
                                         pack2bf(acc[i][2], acc[i][3]));
                ushortt* r1 = hB + ((size_t)(h0 + 1) * Nn + m) * 64 + tn * 4;
                *(uint2*)r1 = make_uint2(pack2bf(acc[i][4], acc[i][5]),
                                         pack2bf(acc[i][6], acc[i][7]));
            }
            int c0 = n0 + tn * 4, c1 = c0 + 64;
            float ps0 = acc[i][0] * atts[c0] + acc[i][1] * atts[c0 + 1]
                      + acc[i][2] * atts[c0 + 2] + acc[i][3] * atts[c0 + 3];
            float pd0 = acc[i][0] * attd[c0] + acc[i][1] * attd[c0 + 1]
                      + acc[i][2] * attd[c0 + 2] + acc[i][3] * attd[c0 + 3];
            float ps1 = acc[i][4] * atts[c1] + acc[i][5] * atts[c1 + 1]
                      + acc[i][6] * atts[c1 + 2] + acc[i][7] * atts[c1 + 3];
            float pd1 = acc[i][4] * attd[c1] + acc[i][5] * attd[c1 + 1]
                      + acc[i][6] * attd[c1 + 2] + acc[i][7] * attd[c1 + 3];
            #pragma unroll
            for (int o = 1; o < 16; o <<= 1) {
                ps0 += __shfl_xor(ps0, o); pd0 += __shfl_xor(pd0, o);
                ps1 += __shfl_xor(ps1, o); pd1 += __shfl_xor(pd1, o);
            }
            if (tn == 0 && valid) {
                a_s[(size_t)m * 4 + h0]     = ps0;
                a_s[(size_t)m * 4 + h0 + 1] = ps1;
                a_d[(size_t)m * 4 + h0]     = pd0;
                a_d[(size_t)m * 4 + h0 + 1] = pd1;
            }
        } else {
            if (valid) {
                ushortt* row = hB + (size_t)m * 64 + tn * 4;
                *(uint2*)row = make_uint2(pack2bf(acc[i][0], acc[i][1]),
                                          pack2bf(acc[i][2], acc[i][3]));
            }
            float ps = 0.f, pd = 0.f;
            #pragma unroll
            for (int j = 0; j < 4; ++j) {
                int c = tn * 4 + j;
                float as = (c < NC) ? atts[c] : 0.f;
                float ad = (c < NC) ? attd[c] : 0.f;
                ps = fmaf(acc[i][j], as, ps);
                pd = fmaf(acc[i][j], ad, pd);
            }
            #pragma unroll
            for (int o = 1; o < 16; o <<= 1) {
                ps += __shfl_xor(ps, o); pd += __shfl_xor(pd, o);
            }
            if (tn == 0 && valid) { a_s[m] = ps; a_d[m] = pd; }
        }
    }
}

// ---------------- alpha layer 1: edge-parallel, 4 heads -> alH[h*Etot + j] fp16 ----------------
__launch_bounds__(256)
__global__ void alpha4e_kernel(const int* __restrict__ csr, const int* __restrict__ dstv,
                               const float* __restrict__ a_s4, const float* __restrict__ a_d4,
                               __half* __restrict__ alH, int Etot) {
    int j = blockIdx.x * 256 + threadIdx.x;
    if (j >= Etot) return;
    int s = csr[j], d = dstv[j];
    fx4 as = *(const fx4*)&a_s4[(size_t)s * 4];
    fx4 ad = *(const fx4*)&a_d4[(size_t)d * 4];
    #pragma unroll
    for (int h = 0; h < 4; ++h) {
        float v = as[h] + ad[h];
        v = v > 0.f ? v : NEG_SLOPE * v;
        alH[(size_t)h * Etot + j] = __float2half(__expf(v));
    }
}

// ---------------- PV layer 1: head-split (head = blockIdx&3 -> XCD-pinned slice) ----------------
// hBH head-major [head][node][64] (128B rows), alH fp16 per-head streams.
// Wave=node, 8 lanes/edge, unroll 2; ssum in-walk; BN+ELU -> bf16 actb[node][256] slice.
__launch_bounds__(256)
__global__ void pv1h_kernel(const int* __restrict__ off, const int* __restrict__ csr,
                            const __half* __restrict__ alH, const ushortt* __restrict__ hBH,
                            const float* __restrict__ bnsc, const float* __restrict__ bnsh,
                            ushortt* __restrict__ actb, int N, int Etot) {
    int hd = blockIdx.x & 3;
    int node = (blockIdx.x >> 2) * 4 + (threadIdx.x >> 6);
    int lane = threadIdx.x & 63;
    if (node >= N) return;
    int grp = lane >> 3, sub = lane & 7;
    unsigned subb = (unsigned)(sub * 16);
    int beg = off[node], end = off[node + 1], deg = end - beg;
    const __half* alh = alH + (size_t)hd * Etot;
    const char* hBb = (const char*)(hBH + (size_t)hd * N * 64);
    float acc[8] = {};
    float ssum = 0.f;
    int nt = (deg + 7) >> 3;
    int j = beg + grp;
    int t = 0;
    for (; t + 2 <= nt; t += 2, j += 16) {
        int jA = j, jB = j + 8;
        bool vA = jA < end, vB = jB < end;
        int iA = vA ? jA : beg, iB = vB ? jB : beg;
        int sA = csr[iA], sB = csr[iB];
        float aA = vA ? __half2float(alh[iA]) : 0.f;
        float aB = vB ? __half2float(alh[iB]) : 0.f;
        uint4 hA = *(const uint4*)(hBb + (unsigned)sA * 128u + subb);
        uint4 hBv = *(const uint4*)(hBb + (unsigned)sB * 128u + subb);
        acc8(acc, aA, hA);
        acc8(acc, aB, hBv);
        ssum += aA + aB;
    }
    for (; t < nt; ++t, j += 8) {
        bool v = j < end;
        int idx = v ? j : beg;
        int s = csr[idx];
        float a = v ? __half2float(alh[idx]) : 0.f;
        uint4 h = *(const uint4*)(hBb + (unsigned)s * 128u + subb);
        acc8(acc, a, h);
        ssum += a;
    }
    #pragma unroll
    for (int o = 8; o <= 32; o <<= 1) {
        #pragma unroll
        for (int i = 0; i < 8; ++i) acc[i] += __shfl_xor(acc[i], o);
        ssum += __shfl_xor(ssum, o);
    }
    if (lane < 8) {
        float inv = 1.f / (ssum + 1e-16f);
        int gc = hd * 64 + lane * 8;
        float o[8];
        #pragma unroll
        for (int i = 0; i < 8; ++i) {
            float v = acc[i] * inv * bnsc[gc + i] + bnsh[gc + i];
            o[i] = v > 0.f ? v : expm1f(v);
        }
        uint4 pk = make_uint4(pack2bf(o[0], o[1]), pack2bf(o[2], o[3]),
                              pack2bf(o[4], o[5]), pack2bf(o[6], o[7]));
        *(uint4*)&actb[(size_t)node * 256 + gc] = pk;
    }
}

// ---------------- PV layer 2: wave=node, 8 lanes/edge, inline exp; BN+ELU -> bf16 act2 ----------------
__launch_bounds__(256)
__global__ void pv2_kernel(const int* __restrict__ off, const int* __restrict__ csr,
                           const float* __restrict__ a_s, const float* __restrict__ a_d,
                           const ushortt* __restrict__ hB,
                           const float* __restrict__ bnsc, const float* __restrict__ bnsh,
                           ushortt* __restrict__ act2b, int N) {
    int node = blockIdx.x * 4 + (threadIdx.x >> 6);
    int lane = threadIdx.x & 63;
    if (node >= N) return;
    int grp = lane >> 3, sub = lane & 7;
    unsigned subb = (unsigned)(sub * 16);
    int beg = off[node], end = off[node + 1], deg = end - beg;
    float ad = a_d[node];
    const char* hBb = (const char*)hB;
    float acc[8] = {};
    float ssum = 0.f;
    int nt = (deg + 7) >> 3;
    int j = beg + grp;
    int t = 0;
    for (; t + 2 <= nt; t += 2, j += 16) {
        int jA = j, jB = j + 8;
        bool vA = jA < end, vB = jB < end;
        int iA = vA ? jA : beg, iB = vB ? jB : beg;
        int sA = csr[iA], sB = csr[iB];
        float wA = a_s[sA] + ad; wA = wA > 0.f ? wA : NEG_SLOPE * wA;
        float wB = a_s[sB] + ad; wB = wB > 0.f ? wB : NEG_SLOPE * wB;
        float aA = vA ? __expf(wA) : 0.f;
        float aB = vB ? __expf(wB) : 0.f;
        uint4 hA = *(const uint4*)(hBb + (unsigned)sA * 128u + subb);
        uint4 hBv = *(const uint4*)(hBb + (unsigned)sB * 128u + subb);
        acc8(acc, aA, hA);
        acc8(acc, aB, hBv);
        ssum += aA + aB;
    }
    for (; t < nt; ++t, j += 8) {
        bool v = j < end;
        int idx = v ? j : beg;
        int s = csr[idx];
        float w = a_s[s] + ad; w = w > 0.f ? w : NEG_SLOPE * w;
        float a = v ? __expf(w) : 0.f;
        uint4 h = *(const uint4*)(hBb + (unsigned)s * 128u + subb);
        acc8(acc, a, h);
        ssum += a;
    }
    #pragma unroll
    for (int o = 8; o <= 32; o <<= 1) {
        #pragma unroll
        for (int i = 0; i < 8; ++i) acc[i] += __shfl_xor(acc[i], o);
        ssum += __shfl_xor(ssum, o);
    }
    if (lane < 8) {
        float inv = 1.f / (ssum + 1e-16f);
        int g = lane * 8;
        float o[8];
        #pragma unroll
        for (int i = 0; i < 8; ++i) {
            float v = acc[i] * inv * bnsc[256 + g + i] + bnsh[256 + g + i];
            o[i] = v > 0.f ? v : expm1f(v);
        }
        uint4 pk = make_uint4(pack2bf(o[0], o[1]), pack2bf(o[2], o[3]),
                              pack2bf(o[4], o[5]), pack2bf(o[6], o[7]));
        *(uint4*)&act2b[(size_t)node * 64 + g] = pk;
    }
}

// ---------------- PV layer 3: wave=node; fused bias + log_softmax -> out ----------------
__launch_bounds__(256)
__global__ void pv3_kernel(const int* __restrict__ off, const int* __restrict__ csr,
                           const float* __restrict__ a_s, const float* __restrict__ a_d,
                           const ushortt* __restrict__ hB, const float* __restrict__ bias,
                           float* __restrict__ out, int N) {
    int node = blockIdx.x * 4 + (threadIdx.x >> 6);
    int lane = threadIdx.x & 63;
    if (node >= N) return;
    int grp = lane >> 3, sub = lane & 7;
    unsigned subb = (unsigned)(sub * 16);
    int beg = off[node], end = off[node + 1];
    float ad = a_d[node];
    const char* hBb = (const char*)hB;
    float acc[8] = {};
    float ssum = 0.f;
    for (int j0 = beg; j0 < end; j0 += 8) {
        int j = j0 + grp;
        bool v = j < end;
        int idx = v ? j : beg;
        int s = csr[idx];
        float w = a_s[s] + ad; w = w > 0.f ? w : NEG_SLOPE * w;
        float a = v ? __expf(w) : 0.f;
        uint4 h = *(const uint4*)(hBb + (unsigned)s * 128u + subb);
        acc8(acc, a, h);
        ssum += a;
    }
    #pragma unroll
    for (int o = 8; o <= 32; o <<= 1) {
        #pragma unroll
        for (int i = 0; i < 8; ++i) acc[i] += __shfl_xor(acc[i], o);
        ssum += __shfl_xor(ssum, o);
    }
    float inv = 1.f / (ssum + 1e-16f);
    int g = lane * 8;
    bool act8 = lane < 5;
    float val[8];
    float mx = -INFINITY;
    #pragma unroll
    for (int i = 0; i < 8; ++i) {
        val[i] = act8 ? (acc[i] * inv + bias[act8 ? (g + i) : 0]) : -INFINITY;
        mx = fmaxf(mx, val[i]);
    }
    #pragma unroll
    for (int o = 1; o < 8; o <<= 1) mx = fmaxf(mx, __shfl_xor(mx, o));
    float se = 0.f;
    if (act8) {
        #pragma unroll
        for (int i = 0; i < 8; ++i) se += __expf(val[i] - mx);
    }
    #pragma unroll
    for (int o = 1; o < 8; o <<= 1) se += __shfl_xor(se, o);
    if (act8) {
        float lse = mx + logf(se);
        float* dst = &out[(size_t)node * 40 + g];
        fx4 v0 = {val[0] - lse, val[1] - lse, val[2] - lse, val[3] - lse};
        fx4 v1 = {val[4] - lse, val[5] - lse, val[6] - lse, val[7] - lse};
        *(fx4*)dst = v0;
        *(fx4*)(dst + 4) = v1;
    }
}

// ---------------- host ----------------
extern "C" void kernel_launch(void* const* d_in, const int* in_sizes, int n_in,
                              void* d_out, int out_size, void* d_ws, size_t ws_size,
                              hipStream_t stream) {
    const float* x      = (const float*)d_in[0];
    const int*   ei     = (const int*)d_in[1];
    const float* W1     = (const float*)d_in[2];
    const float* att_s1 = (const float*)d_in[3];
    const float* att_d1 = (const float*)d_in[4];
    const float* b1     = (const float*)d_in[5];
    const float* bn1g   = (const float*)d_in[6];
    const float* bn1b   = (const float*)d_in[7];
    const float* bn1m   = (const float*)d_in[8];
    const float* bn1v   = (const float*)d_in[9];
    const float* W2     = (const float*)d_in[10];
    const float* att_s2 = (const float*)d_in[11];
    const float* att_d2 = (const float*)d_in[12];
    const float* b2     = (const float*)d_in[13];
    const float* bn2g   = (const float*)d_in[14];
    const float* bn2b   = (const float*)d_in[15];
    const float* bn2m   = (const float*)d_in[16];
    const float* bn2v   = (const float*)d_in[17];
    const float* W3     = (const float*)d_in[18];
    const float* att_s3 = (const float*)d_in[19];
    const float* att_d3 = (const float*)d_in[20];
    const float* b3     = (const float*)d_in[21];

    const int N    = in_sizes[0] / IN_DIM;
    const int E    = in_sizes[1] / 2;
    const int Etot = E + N;

    int*   wsi = (int*)d_ws;
    float* wsf = (float*)d_ws;
    size_t p = 0;
    int*   off    = wsi + p; p += (size_t)N + 16;  p = (p + 3) & ~(size_t)3;
    int*   cursor = wsi + p; p += (size_t)N;       p = (p + 3) & ~(size_t)3;
    int*   flag   = wsi + p; p += 16;
    int*   csr    = wsi + p; p += (size_t)Etot;    p = (p + 3) & ~(size_t)3;
    int*   dstv   = wsi + p; p += (size_t)Etot;    p = (p + 3) & ~(size_t)3;
    float* a_s4   = wsf + p; p += (size_t)N * 4;
    float* a_d4   = wsf + p; p += (size_t)N * 4;
    float* bnsc   = wsf + p; p += 384;
    float* bnsh   = wsf + p; p += 384;
    size_t H = p;            p += (size_t)N * 128;   // hB1H (head-major) / hB23
    size_t A1 = p;           p += (size_t)N * 128;   // actb  (N*256 bf16)
    size_t A2 = p;           p += (size_t)N * 32;    // act2b (N*64 bf16)
    __half* alH = (__half*)(wsf + p); p += (size_t)Etot * 2 + 16;  // fp16, head-major streams
    if (ws_size < p * 4) return;

    ushortt* hB1H  = (ushortt*)(wsf + H);
    ushortt* hB23  = (ushortt*)(wsf + H);
    ushortt* actb  = (ushortt*)(wsf + A1);
    ushortt* act2b = (ushortt*)(wsf + A2);

    float* outp = (float*)d_out;

    // ---- CSR build ----
    hipMemsetAsync(off, 0, ((size_t)N + 1) * sizeof(int), stream);
    detect_kernel<<<1, 256, 0, stream>>>((const unsigned int*)ei, flag);
    {
        int blocks = (Etot + 255) / 256;
        hist_kernel<<<blocks, 256, 0, stream>>>(ei, flag, off, E, Etot);
        scan_kernel<<<1, 1024, 0, stream>>>(off, N + 1);
        hipMemcpyAsync(cursor, off, (size_t)N * sizeof(int), hipMemcpyDeviceToDevice, stream);
        scatter_kernel<<<blocks, 256, 0, stream>>>(ei, flag, cursor, csr, dstv, E, Etot);
    }
    prep_bn_kernel<<<1, 384, 0, stream>>>(b1, bn1g, bn1b, bn1m, bn1v,
                                          b2, bn2g, bn2b, bn2m, bn2v, bnsc, bnsh);

    const int gm = (N + 127) / 128;
    const int nb4 = (N + 3) / 4;
    const int eb = (Etot + 255) / 256;

    // ---- layer 1 ----
    gemm_fused_kernel<128, 128, 8, 256, 256, false, true>
        <<<dim3(gm, 2), 256, 0, stream>>>(x, W1, hB1H, att_s1, att_d1, a_s4, a_d4, N, N);
    alpha4e_kernel<<<eb, 256, 0, stream>>>(csr, dstv, a_s4, a_d4, alH, Etot);
    pv1h_kernel<<<nb4 * 4, 256, 0, stream>>>(off, csr, alH, hB1H, bnsc, bnsh, actb, N, Etot);

    // ---- layer 2 ----
    gemm_fused_kernel<256, 64, 4, 64, 64, true, false>
        <<<dim3(gm, 1), 256, 0, stream>>>(actb, W2, hB23, att_s2, att_d2, a_s4, a_d4, N, N);
    pv2_kernel<<<nb4, 256, 0, stream>>>(off, csr, a_s4, a_d4, hB23, bnsc, bnsh, act2b, N);

    // ---- layer 3 (log_softmax fused into PV epilogue) ----
    gemm_fused_kernel<64, 64, 4, 40, 40, true, false>
        <<<dim3(gm, 1), 256, 0, stream>>>(act2b, W3, hB23, att_s3, att_d3, a_s4, a_d4, N, N);
    pv3_kernel<<<nb4, 256, 0, stream>>>(off, csr, a_s4, a_d4, hB23, b3, outp, N);
}

// Round 13
// 776.015 us; speedup vs baseline: 1.1825x; 1.1825x over previous
//
#include <hip/hip_runtime.h>
#include <hip/hip_fp16.h>
#include <cstdint>

#define IN_DIM   128
#define HIDC     64
#define HEADS    4
#define OUT_DIM  40
#define NEG_SLOPE 0.2f
#define BN_EPS   1e-5f

typedef unsigned short ushortt;
typedef float fx4 __attribute__((ext_vector_type(4)));

__device__ __forceinline__ float bfval(ushortt u) {
    return __uint_as_float(((unsigned)u) << 16);
}
__device__ __forceinline__ ushortt f2bf(float f) {
    unsigned u = __float_as_uint(f);
    u += 0x7fffu + ((u >> 16) & 1u);
    return (ushortt)(u >> 16);
}
__device__ __forceinline__ unsigned pack2bf(float a, float b) {
    return (unsigned)f2bf(a) | ((unsigned)f2bf(b) << 16);
}

// acc[0..7] += a * bf16x8(h)
__device__ __forceinline__ void acc8(float* acc, float a, uint4 h) {
    unsigned u;
    u = h.x;
    acc[0] = fmaf(a, __uint_as_float(u << 16), acc[0]);
    acc[1] = fmaf(a, __uint_as_float(u & 0xffff0000u), acc[1]);
    u = h.y;
    acc[2] = fmaf(a, __uint_as_float(u << 16), acc[2]);
    acc[3] = fmaf(a, __uint_as_float(u & 0xffff0000u), acc[3]);
    u = h.z;
    acc[4] = fmaf(a, __uint_as_float(u << 16), acc[4]);
    acc[5] = fmaf(a, __uint_as_float(u & 0xffff0000u), acc[5]);
    u = h.w;
    acc[6] = fmaf(a, __uint_as_float(u << 16), acc[6]);
    acc[7] = fmaf(a, __uint_as_float(u & 0xffff0000u), acc[7]);
}

// ---------------- CSR build ----------------
__global__ void detect_kernel(const unsigned int* __restrict__ e, int* __restrict__ flag) {
    __shared__ int any;
    if (threadIdx.x == 0) any = 0;
    __syncthreads();
    for (int i = threadIdx.x; i < 1024; i += 256)
        if (e[2 * i + 1] != 0u) any = 1;
    __syncthreads();
    if (threadIdx.x == 0) flag[0] = any ? 0 : 1;   // 1 => int64
}

__device__ __forceinline__ int load_idx(const int* ei, int is64, long long pos) {
    return is64 ? ei[2 * pos] : ei[pos];
}

__global__ void hist_kernel(const int* __restrict__ ei, const int* __restrict__ flag,
                            int* __restrict__ deg, int E, int Etot) {
    int i = blockIdx.x * 256 + threadIdx.x;
    if (i >= Etot) return;
    int is64 = flag[0];
    int dst = (i < E) ? load_idx(ei, is64, (long long)E + i) : (i - E);
    atomicAdd(&deg[dst], 1);
}

__global__ void scan_kernel(int* __restrict__ data, int n) {
    __shared__ int wsum[16];
    __shared__ int chunk_total;
    int lane = threadIdx.x & 63;
    int w = threadIdx.x >> 6;
    int carry = 0;
    for (int base = 0; base < n; base += 1024) {
        int i = base + (int)threadIdx.x;
        int v = (i < n) ? data[i] : 0;
        int x = v;
        #pragma unroll
        for (int ofs = 1; ofs < 64; ofs <<= 1) {
            int y = __shfl_up(x, ofs);
            if (lane >= ofs) x += y;
        }
        if (lane == 63) wsum[w] = x;
        __syncthreads();
        if (w == 0) {
            int s = (lane < 16) ? wsum[lane] : 0;
            #pragma unroll
            for (int ofs = 1; ofs < 16; ofs <<= 1) {
                int y = __shfl_up(s, ofs);
                if (lane >= ofs) s += y;
            }
            if (lane < 16) wsum[lane] = s;
            if (lane == 15) chunk_total = s;
        }
        __syncthreads();
        int woff = (w > 0) ? wsum[w - 1] : 0;
        if (i < n) data[i] = (x + woff) - v + carry;
        int ct = chunk_total;
        __syncthreads();
        carry += ct;
    }
}

__global__ void scatter_kernel(const int* __restrict__ ei, const int* __restrict__ flag,
                               int* __restrict__ cursor, int* __restrict__ csr,
                               int* __restrict__ dstv, int E, int Etot) {
    int i = blockIdx.x * 256 + threadIdx.x;
    if (i >= Etot) return;
    int is64 = flag[0];
    int src, dst;
    if (i < E) {
        src = load_idx(ei, is64, i);
        dst = load_idx(ei, is64, (long long)E + i);
    } else {
        src = dst = i - E;
    }
    int pos = atomicAdd(&cursor[dst], 1);
    csr[pos] = src;
    dstv[pos] = dst;
}

// ---------------- fold bias+BN into scale/shift ----------------
__global__ void prep_bn_kernel(const float* b1, const float* g1, const float* bb1,
                               const float* m1, const float* v1,
                               const float* b2, const float* g2, const float* bb2,
                               const float* m2, const float* v2,
                               float* __restrict__ bnsc, float* __restrict__ bnsh) {
    int t = threadIdx.x;
    if (t < 256) {
        float s = g1[t] * rsqrtf(v1[t] + BN_EPS);
        bnsc[t] = s;
        bnsh[t] = (b1[t] - m1[t]) * s + bb1[t];
    } else if (t < 320) {
        int c = t - 256;
        float s = g2[c] * rsqrtf(v2[c] + BN_EPS);
        bnsc[t] = s;
        bnsh[t] = (b2[c] - m2[c]) * s + bb2[c];
    }
}

// ---------------- register-tiled GEMM + fused attention dots -> bf16 h ----------------
// L1MODE: h row-major [node][256]; a_s4/a_d4 node-major [node*4+head].
// else:   h row-major [node][64]; a_s[node], a_d[node].
template <int K, int BN, int TN, int NC, int LDW, bool ABF16, bool L1MODE>
__launch_bounds__(256)
__global__ void gemm_fused_kernel(const void* __restrict__ Av, const float* __restrict__ W,
                                  ushortt* __restrict__ hB,
                                  const float* __restrict__ atts, const float* __restrict__ attd,
                                  float* __restrict__ a_s, float* __restrict__ a_d, int M) {
    __shared__ float Al[8][128];
    __shared__ float Wl[8][BN];
    int m0 = blockIdx.x * 128;
    int n0 = blockIdx.y * BN;
    int t = threadIdx.x;
    int tm = t >> 4, tn = t & 15;
    float acc[8][TN] = {};
    int r = t >> 1, kq = (t & 1) * 4;

    for (int k0 = 0; k0 < K; k0 += 8) {
        if constexpr (ABF16) {
            const ushortt* A = (const ushortt*)Av;
            uint2 av = make_uint2(0u, 0u);
            if (m0 + r < M) av = *(const uint2*)(A + (size_t)(m0 + r) * K + k0 + kq);
            Al[kq + 0][r] = bfval((ushortt)(av.x & 0xffffu));
            Al[kq + 1][r] = bfval((ushortt)(av.x >> 16));
            Al[kq + 2][r] = bfval((ushortt)(av.y & 0xffffu));
            Al[kq + 3][r] = bfval((ushortt)(av.y >> 16));
        } else {
            const float* A = (const float*)Av;
            float4 av = make_float4(0.f, 0.f, 0.f, 0.f);
            if (m0 + r < M) av = *(const float4*)&A[(size_t)(m0 + r) * K + k0 + kq];
            Al[kq + 0][r] = av.x; Al[kq + 1][r] = av.y;
            Al[kq + 2][r] = av.z; Al[kq + 3][r] = av.w;
        }
        if constexpr (BN == 128) {
            int kk = t >> 5, c4 = (t & 31) * 4;
            *(float4*)&Wl[kk][c4] = *(const float4*)&W[(size_t)(k0 + kk) * LDW + n0 + c4];
        } else {
            int kk = t >> 5, c2 = (t & 31) * 2;
            float2 wv = make_float2(0.f, 0.f);
            if (c2 + 2 <= NC) wv = *(const float2*)&W[(size_t)(k0 + kk) * LDW + n0 + c2];
            *(float2*)&Wl[kk][c2] = wv;
        }
        __syncthreads();
        #pragma unroll
        for (int k = 0; k < 8; ++k) {
            float4 a0 = *(const float4*)&Al[k][tm * 8];
            float4 a1 = *(const float4*)&Al[k][tm * 8 + 4];
            float aa[8] = {a0.x, a0.y, a0.z, a0.w, a1.x, a1.y, a1.z, a1.w};
            if constexpr (TN == 8) {
                float4 w0 = *(const float4*)&Wl[k][tn * 4];
                float4 w1 = *(const float4*)&Wl[k][64 + tn * 4];
                float ww[8] = {w0.x, w0.y, w0.z, w0.w, w1.x, w1.y, w1.z, w1.w};
                #pragma unroll
                for (int i = 0; i < 8; ++i)
                    #pragma unroll
                    for (int j = 0; j < 8; ++j)
                        acc[i][j] = fmaf(aa[i], ww[j], acc[i][j]);
            } else {
                float4 w0 = *(const float4*)&Wl[k][tn * 4];
                float ww[4] = {w0.x, w0.y, w0.z, w0.w};
                #pragma unroll
                for (int i = 0; i < 8; ++i)
                    #pragma unroll
                    for (int j = 0; j < 4; ++j)
                        acc[i][j] = fmaf(aa[i], ww[j], acc[i][j]);
            }
        }
        __syncthreads();
    }
    // ---- epilogue: bf16 stores + fused per-row attention dots ----
    #pragma unroll
    for (int i = 0; i < 8; ++i) {
        int m = m0 + tm * 8 + i;
        bool valid = m < M;
        if constexpr (L1MODE) {
            int h0 = n0 >> 6;
            if (valid) {
                ushortt* row = hB + (size_t)m * 256 + n0;
                *(uint2*)(row + tn * 4) = make_uint2(pack2bf(acc[i][0], acc[i][1]),
                                                     pack2bf(acc[i][2], acc[i][3]));
                *(uint2*)(row + 64 + tn * 4) = make_uint2(pack2bf(acc[i][4], acc[i][5]),
                                                          pack2bf(acc[i][6], acc[i][7]));
            }
            int c0 = n0 + tn * 4, c1 = c0 + 64;
            float ps0 = acc[i][0] * atts[c0] + acc[i][1] * atts[c0 + 1]
                      + acc[i][2] * atts[c0 + 2] + acc[i][3] * atts[c0 + 3];
            float pd0 = acc[i][0] * attd[c0] + acc[i][1] * attd[c0 + 1]
                      + acc[i][2] * attd[c0 + 2] + acc[i][3] * attd[c0 + 3];
            float ps1 = acc[i][4] * atts[c1] + acc[i][5] * atts[c1 + 1]
                      + acc[i][6] * atts[c1 + 2] + acc[i][7] * atts[c1 + 3];
            float pd1 = acc[i][4] * attd[c1] + acc[i][5] * attd[c1 + 1]
                      + acc[i][6] * attd[c1 + 2] + acc[i][7] * attd[c1 + 3];
            #pragma unroll
            for (int o = 1; o < 16; o <<= 1) {
                ps0 += __shfl_xor(ps0, o); pd0 += __shfl_xor(pd0, o);
                ps1 += __shfl_xor(ps1, o); pd1 += __shfl_xor(pd1, o);
            }
            if (tn == 0 && valid) {
                a_s[(size_t)m * 4 + h0]     = ps0;
                a_s[(size_t)m * 4 + h0 + 1] = ps1;
                a_d[(size_t)m * 4 + h0]     = pd0;
                a_d[(size_t)m * 4 + h0 + 1] = pd1;
            }
        } else {
            if (valid) {
                ushortt* row = hB + (size_t)m * 64 + tn * 4;
                *(uint2*)row = make_uint2(pack2bf(acc[i][0], acc[i][1]),
                                          pack2bf(acc[i][2], acc[i][3]));
            }
            float ps = 0.f, pd = 0.f;
            #pragma unroll
            for (int j = 0; j < 4; ++j) {
                int c = tn * 4 + j;
                float as = (c < NC) ? atts[c] : 0.f;
                float ad = (c < NC) ? attd[c] : 0.f;
                ps = fmaf(acc[i][j], as, ps);
                pd = fmaf(acc[i][j], ad, pd);
            }
            #pragma unroll
            for (int o = 1; o < 16; o <<= 1) {
                ps += __shfl_xor(ps, o); pd += __shfl_xor(pd, o);
            }
            if (tn == 0 && valid) { a_s[m] = ps; a_d[m] = pd; }
        }
    }
}

// ---------------- alpha layer 1: edge-parallel, 4 heads -> alH[h*Etot + j] fp16 ----------------
__launch_bounds__(256)
__global__ void alpha4e_kernel(const int* __restrict__ csr, const int* __restrict__ dstv,
                               const float* __restrict__ a_s4, const float* __restrict__ a_d4,
                               __half* __restrict__ alH, int Etot) {
    int j = blockIdx.x * 256 + threadIdx.x;
    if (j >= Etot) return;
    int s = csr[j], d = dstv[j];
    fx4 as = *(const fx4*)&a_s4[(size_t)s * 4];
    fx4 ad = *(const fx4*)&a_d4[(size_t)d * 4];
    #pragma unroll
    for (int h = 0; h < 4; ++h) {
        float v = as[h] + ad[h];
        v = v > 0.f ? v : NEG_SLOPE * v;
        alH[(size_t)h * Etot + j] = __float2half(__expf(v));
    }
}

// ---------------- PV layer 1: wave=node, 2 edges/step, 32 lanes/edge, unroll 4 ----------------
// Reads fp16 unnormalized alpha (per-head streams); accumulates per-head ssum in-walk.
__launch_bounds__(256)
__global__ void pv1_kernel(const int* __restrict__ off, const int* __restrict__ csr,
                           const __half* __restrict__ alH, const ushortt* __restrict__ hB,
                           const float* __restrict__ bnsc, const float* __restrict__ bnsh,
                           ushortt* __restrict__ actb, int N, int Etot) {
    int node = blockIdx.x * 4 + (threadIdx.x >> 6);
    int lane = threadIdx.x & 63;
    if (node >= N) return;
    int half = lane >> 5, sub = lane & 31, head = sub >> 3;
    unsigned subb = (unsigned)(sub * 16);
    int beg = off[node], end = off[node + 1], deg = end - beg;
    const __half* alh = alH + (size_t)head * Etot;
    const char* hBb = (const char*)hB;
    float acc[8] = {};
    float ssum = 0.f;
    int nt = (deg + 1) >> 1;
    int j = beg + half;
    int t = 0;
    for (; t + 4 <= nt; t += 4, j += 8) {
        float av[4]; unsigned ro[4];
        #pragma unroll
        for (int q = 0; q < 4; ++q) {
            int jq = j + 2 * q;
            bool v = jq < end;
            int idx = v ? jq : beg;
            int s = csr[idx];
            av[q] = v ? __half2float(alh[idx]) : 0.f;
            ro[q] = (unsigned)s * 512u + subb;
        }
        uint4 h0 = *(const uint4*)(hBb + ro[0]);
        uint4 h1 = *(const uint4*)(hBb + ro[1]);
        uint4 h2 = *(const uint4*)(hBb + ro[2]);
        uint4 h3 = *(const uint4*)(hBb + ro[3]);
        acc8(acc, av[0], h0);
        acc8(acc, av[1], h1);
        acc8(acc, av[2], h2);
        acc8(acc, av[3], h3);
        ssum += (av[0] + av[1]) + (av[2] + av[3]);
    }
    for (; t < nt; ++t, j += 2) {
        bool v = j < end;
        int idx = v ? j : beg;
        int s = csr[idx];
        float a = v ? __half2float(alh[idx]) : 0.f;
        uint4 h = *(const uint4*)(hBb + (unsigned)s * 512u + subb);
        acc8(acc, a, h);
        ssum += a;
    }
    #pragma unroll
    for (int i = 0; i < 8; ++i) acc[i] += __shfl_xor(acc[i], 32);
    ssum += __shfl_xor(ssum, 32);
    if (half == 0) {
        float inv = 1.f / (ssum + 1e-16f);
        int g = sub * 8;
        float o[8];
        #pragma unroll
        for (int i = 0; i < 8; ++i) {
            float v = acc[i] * inv * bnsc[g + i] + bnsh[g + i];
            o[i] = v > 0.f ? v : expm1f(v);
        }
        uint4 pk = make_uint4(pack2bf(o[0], o[1]), pack2bf(o[2], o[3]),
                              pack2bf(o[4], o[5]), pack2bf(o[6], o[7]));
        *(uint4*)&actb[(size_t)node * 256 + g] = pk;
    }
}

// ---------------- PV layer 2: wave=node, 8 lanes/edge, inline exp; BN+ELU -> bf16 act2 ----------------
__launch_bounds__(256)
__global__ void pv2_kernel(const int* __restrict__ off, const int* __restrict__ csr,
                           const float* __restrict__ a_s, const float* __restrict__ a_d,
                           const ushortt* __restrict__ hB,
                           const float* __restrict__ bnsc, const float* __restrict__ bnsh,
                           ushortt* __restrict__ act2b, int N) {
    int node = blockIdx.x * 4 + (threadIdx.x >> 6);
    int lane = threadIdx.x & 63;
    if (node >= N) return;
    int grp = lane >> 3, sub = lane & 7;
    unsigned subb = (unsigned)(sub * 16);
    int beg = off[node], end = off[node + 1], deg = end - beg;
    float ad = a_d[node];
    const char* hBb = (const char*)hB;
    float acc[8] = {};
    float ssum = 0.f;
    int nt = (deg + 7) >> 3;
    int j = beg + grp;
    int t = 0;
    for (; t + 2 <= nt; t += 2, j += 16) {
        int jA = j, jB = j + 8;
        bool vA = jA < end, vB = jB < end;
        int iA = vA ? jA : beg, iB = vB ? jB : beg;
        int sA = csr[iA], sB = csr[iB];
        float wA = a_s[sA] + ad; wA = wA > 0.f ? wA : NEG_SLOPE * wA;
        float wB = a_s[sB] + ad; wB = wB > 0.f ? wB : NEG_SLOPE * wB;
        float aA = vA ? __expf(wA) : 0.f;
        float aB = vB ? __expf(wB) : 0.f;
        uint4 hA = *(const uint4*)(hBb + (unsigned)sA * 128u + subb);
        uint4 hBv = *(const uint4*)(hBb + (unsigned)sB * 128u + subb);
        acc8(acc, aA, hA);
        acc8(acc, aB, hBv);
        ssum += aA + aB;
    }
    for (; t < nt; ++t, j += 8) {
        bool v = j < end;
        int idx = v ? j : beg;
        int s = csr[idx];
        float w = a_s[s] + ad; w = w > 0.f ? w : NEG_SLOPE * w;
        float a = v ? __expf(w) : 0.f;
        uint4 h = *(const uint4*)(hBb + (unsigned)s * 128u + subb);
        acc8(acc, a, h);
        ssum += a;
    }
    #pragma unroll
    for (int o = 8; o <= 32; o <<= 1) {
        #pragma unroll
        for (int i = 0; i < 8; ++i) acc[i] += __shfl_xor(acc[i], o);
        ssum += __shfl_xor(ssum, o);
    }
    if (lane < 8) {
        float inv = 1.f / (ssum + 1e-16f);
        int g = lane * 8;
        float o[8];
        #pragma unroll
        for (int i = 0; i < 8; ++i) {
            float v = acc[i] * inv * bnsc[256 + g + i] + bnsh[256 + g + i];
            o[i] = v > 0.f ? v : expm1f(v);
        }
        uint4 pk = make_uint4(pack2bf(o[0], o[1]), pack2bf(o[2], o[3]),
                              pack2bf(o[4], o[5]), pack2bf(o[6], o[7]));
        *(uint4*)&act2b[(size_t)node * 64 + g] = pk;
    }
}

// ---------------- PV layer 3: wave=node; fused bias + log_softmax -> out ----------------
__launch_bounds__(256)
__global__ void pv3_kernel(const int* __restrict__ off, const int* __restrict__ csr,
                           const float* __restrict__ a_s, const float* __restrict__ a_d,
                           const ushortt* __restrict__ hB, const float* __restrict__ bias,
                           float* __restrict__ out, int N) {
    int node = blockIdx.x * 4 + (threadIdx.x >> 6);
    int lane = threadIdx.x & 63;
    if (node >= N) return;
    int grp = lane >> 3, sub = lane & 7;
    unsigned subb = (unsigned)(sub * 16);
    int beg = off[node], end = off[node + 1];
    float ad = a_d[node];
    const char* hBb = (const char*)hB;
    float acc[8] = {};
    float ssum = 0.f;
    for (int j0 = beg; j0 < end; j0 += 8) {
        int j = j0 + grp;
        bool v = j < end;
        int idx = v ? j : beg;
        int s = csr[idx];
        float w = a_s[s] + ad; w = w > 0.f ? w : NEG_SLOPE * w;
        float a = v ? __expf(w) : 0.f;
        uint4 h = *(const uint4*)(hBb + (unsigned)s * 128u + subb);
        acc8(acc, a, h);
        ssum += a;
    }
    #pragma unroll
    for (int o = 8; o <= 32; o <<= 1) {
        #pragma unroll
        for (int i = 0; i < 8; ++i) acc[i] += __shfl_xor(acc[i], o);
        ssum += __shfl_xor(ssum, o);
    }
    float inv = 1.f / (ssum + 1e-16f);
    int g = lane * 8;
    bool act8 = lane < 5;
    float val[8];
    float mx = -INFINITY;
    #pragma unroll
    for (int i = 0; i < 8; ++i) {
        val[i] = act8 ? (acc[i] * inv + bias[act8 ? (g + i) : 0]) : -INFINITY;
        mx = fmaxf(mx, val[i]);
    }
    #pragma unroll
    for (int o = 1; o < 8; o <<= 1) mx = fmaxf(mx, __shfl_xor(mx, o));
    float se = 0.f;
    if (act8) {
        #pragma unroll
        for (int i = 0; i < 8; ++i) se += __expf(val[i] - mx);
    }
    #pragma unroll
    for (int o = 1; o < 8; o <<= 1) se += __shfl_xor(se, o);
    if (act8) {
        float lse = mx + logf(se);
        float* dst = &out[(size_t)node * 40 + g];
        fx4 v0 = {val[0] - lse, val[1] - lse, val[2] - lse, val[3] - lse};
        fx4 v1 = {val[4] - lse, val[5] - lse, val[6] - lse, val[7] - lse};
        *(fx4*)dst = v0;
        *(fx4*)(dst + 4) = v1;
    }
}

// ---------------- host ----------------
extern "C" void kernel_launch(void* const* d_in, const int* in_sizes, int n_in,
                              void* d_out, int out_size, void* d_ws, size_t ws_size,
                              hipStream_t stream) {
    const float* x      = (const float*)d_in[0];
    const int*   ei     = (const int*)d_in[1];
    const float* W1     = (const float*)d_in[2];
    const float* att_s1 = (const float*)d_in[3];
    const float* att_d1 = (const float*)d_in[4];
    const float* b1     = (const float*)d_in[5];
    const float* bn1g   = (const float*)d_in[6];
    const float* bn1b   = (const float*)d_in[7];
    const float* bn1m   = (const float*)d_in[8];
    const float* bn1v   = (const float*)d_in[9];
    const float* W2     = (const float*)d_in[10];
    const float* att_s2 = (const float*)d_in[11];
    const float* att_d2 = (const float*)d_in[12];
    const float* b2     = (const float*)d_in[13];
    const float* bn2g   = (const float*)d_in[14];
    const float* bn2b   = (const float*)d_in[15];
    const float* bn2m   = (const float*)d_in[16];
    const float* bn2v   = (const float*)d_in[17];
    const float* W3     = (const float*)d_in[18];
    const float* att_s3 = (const float*)d_in[19];
    const float* att_d3 = (const float*)d_in[20];
    const float* b3     = (const float*)d_in[21];

    const int N    = in_sizes[0] / IN_DIM;
    const int E    = in_sizes[1] / 2;
    const int Etot = E + N;

    int*   wsi = (int*)d_ws;
    float* wsf = (float*)d_ws;
    size_t p = 0;
    int*   off    = wsi + p; p += (size_t)N + 16;  p = (p + 3) & ~(size_t)3;
    int*   cursor = wsi + p; p += (size_t)N;       p = (p + 3) & ~(size_t)3;
    int*   flag   = wsi + p; p += 16;
    int*   csr    = wsi + p; p += (size_t)Etot;    p = (p + 3) & ~(size_t)3;
    int*   dstv   = wsi + p; p += (size_t)Etot;    p = (p + 3) & ~(size_t)3;
    float* a_s4   = wsf + p; p += (size_t)N * 4;
    float* a_d4   = wsf + p; p += (size_t)N * 4;
    float* bnsc   = wsf + p; p += 384;
    float* bnsh   = wsf + p; p += 384;
    size_t H = p;            p += (size_t)N * 128;   // hB1 (N*256 bf16) / hB23 (N*64 bf16)
    size_t A1 = p;           p += (size_t)N * 128;   // actb  (N*256 bf16)
    size_t A2 = p;           p += (size_t)N * 32;    // act2b (N*64 bf16)
    __half* alH = (__half*)(wsf + p); p += (size_t)Etot * 2 + 16;  // fp16 alpha, head-major
    if (ws_size < p * 4) return;

    ushortt* hB1   = (ushortt*)(wsf + H);
    ushortt* hB23  = (ushortt*)(wsf + H);
    ushortt* actb  = (ushortt*)(wsf + A1);
    ushortt* act2b = (ushortt*)(wsf + A2);

    float* outp = (float*)d_out;

    // ---- CSR build ----
    hipMemsetAsync(off, 0, ((size_t)N + 1) * sizeof(int), stream);
    detect_kernel<<<1, 256, 0, stream>>>((const unsigned int*)ei, flag);
    {
        int blocks = (Etot + 255) / 256;
        hist_kernel<<<blocks, 256, 0, stream>>>(ei, flag, off, E, Etot);
        scan_kernel<<<1, 1024, 0, stream>>>(off, N + 1);
        hipMemcpyAsync(cursor, off, (size_t)N * sizeof(int), hipMemcpyDeviceToDevice, stream);
        scatter_kernel<<<blocks, 256, 0, stream>>>(ei, flag, cursor, csr, dstv, E, Etot);
    }
    prep_bn_kernel<<<1, 384, 0, stream>>>(b1, bn1g, bn1b, bn1m, bn1v,
                                          b2, bn2g, bn2b, bn2m, bn2v, bnsc, bnsh);

    const int gm = (N + 127) / 128;
    const int nb4 = (N + 3) / 4;
    const int eb = (Etot + 255) / 256;

    // ---- layer 1 ----
    gemm_fused_kernel<128, 128, 8, 256, 256, false, true>
        <<<dim3(gm, 2), 256, 0, stream>>>(x, W1, hB1, att_s1, att_d1, a_s4, a_d4, N);
    alpha4e_kernel<<<eb, 256, 0, stream>>>(csr, dstv, a_s4, a_d4, alH, Etot);
    pv1_kernel<<<nb4, 256, 0, stream>>>(off, csr, alH, hB1, bnsc, bnsh, actb, N, Etot);

    // ---- layer 2 ----
    gemm_fused_kernel<256, 64, 4, 64, 64, true, false>
        <<<dim3(gm, 1), 256, 0, stream>>>(actb, W2, hB23, att_s2, att_d2, a_s4, a_d4, N);
    pv2_kernel<<<nb4, 256, 0, stream>>>(off, csr, a_s4, a_d4, hB23, bnsc, bnsh, act2b, N);

    // ---- layer 3 (log_softmax fused into PV epilogue) ----
    gemm_fused_kernel<64, 64, 4, 40, 40, true, false>
        <<<dim3(gm, 1), 256, 0, stream>>>(act2b, W3, hB23, att_s3, att_d3, a_s4, a_d4, N);
    pv3_kernel<<<nb4, 256, 0, stream>>>(off, csr, a_s4, a_d4, hB23, b3, outp, N);
}

// Round 14
// 704.382 us; speedup vs baseline: 1.3028x; 1.1017x over previous
//
#include <hip/hip_runtime.h>
#include <hip/hip_fp16.h>
#include <cstdint>

#define IN_DIM   128
#define HIDC     64
#define HEADS    4
#define OUT_DIM  40
#define NEG_SLOPE 0.2f
#define BN_EPS   1e-5f

typedef unsigned short ushortt;
typedef float fx4 __attribute__((ext_vector_type(4)));
typedef short bf16x8 __attribute__((ext_vector_type(8)));

__device__ __forceinline__ float bfval(ushortt u) {
    return __uint_as_float(((unsigned)u) << 16);
}
__device__ __forceinline__ ushortt f2bf(float f) {
    unsigned u = __float_as_uint(f);
    u += 0x7fffu + ((u >> 16) & 1u);
    return (ushortt)(u >> 16);
}
__device__ __forceinline__ unsigned pack2bf(float a, float b) {
    return (unsigned)f2bf(a) | ((unsigned)f2bf(b) << 16);
}

// acc[0..7] += a * bf16x8(h)
__device__ __forceinline__ void acc8(float* acc, float a, uint4 h) {
    unsigned u;
    u = h.x;
    acc[0] = fmaf(a, __uint_as_float(u << 16), acc[0]);
    acc[1] = fmaf(a, __uint_as_float(u & 0xffff0000u), acc[1]);
    u = h.y;
    acc[2] = fmaf(a, __uint_as_float(u << 16), acc[2]);
    acc[3] = fmaf(a, __uint_as_float(u & 0xffff0000u), acc[3]);
    u = h.z;
    acc[4] = fmaf(a, __uint_as_float(u << 16), acc[4]);
    acc[5] = fmaf(a, __uint_as_float(u & 0xffff0000u), acc[5]);
    u = h.w;
    acc[6] = fmaf(a, __uint_as_float(u << 16), acc[6]);
    acc[7] = fmaf(a, __uint_as_float(u & 0xffff0000u), acc[7]);
}

// ---------------- CSR build ----------------
__global__ void detect_kernel(const unsigned int* __restrict__ e, int* __restrict__ flag) {
    __shared__ int any;
    if (threadIdx.x == 0) any = 0;
    __syncthreads();
    for (int i = threadIdx.x; i < 1024; i += 256)
        if (e[2 * i + 1] != 0u) any = 1;
    __syncthreads();
    if (threadIdx.x == 0) flag[0] = any ? 0 : 1;   // 1 => int64
}

__device__ __forceinline__ int load_idx(const int* ei, int is64, long long pos) {
    return is64 ? ei[2 * pos] : ei[pos];
}

__global__ void hist_kernel(const int* __restrict__ ei, const int* __restrict__ flag,
                            int* __restrict__ deg, int E, int Etot) {
    int i = blockIdx.x * 256 + threadIdx.x;
    if (i >= Etot) return;
    int is64 = flag[0];
    int dst = (i < E) ? load_idx(ei, is64, (long long)E + i) : (i - E);
    atomicAdd(&deg[dst], 1);
}

__global__ void scan_kernel(int* __restrict__ data, int n) {
    __shared__ int wsum[16];
    __shared__ int chunk_total;
    int lane = threadIdx.x & 63;
    int w = threadIdx.x >> 6;
    int carry = 0;
    for (int base = 0; base < n; base += 1024) {
        int i = base + (int)threadIdx.x;
        int v = (i < n) ? data[i] : 0;
        int x = v;
        #pragma unroll
        for (int ofs = 1; ofs < 64; ofs <<= 1) {
            int y = __shfl_up(x, ofs);
            if (lane >= ofs) x += y;
        }
        if (lane == 63) wsum[w] = x;
        __syncthreads();
        if (w == 0) {
            int s = (lane < 16) ? wsum[lane] : 0;
            #pragma unroll
            for (int ofs = 1; ofs < 16; ofs <<= 1) {
                int y = __shfl_up(s, ofs);
                if (lane >= ofs) s += y;
            }
            if (lane < 16) wsum[lane] = s;
            if (lane == 15) chunk_total = s;
        }
        __syncthreads();
        int woff = (w > 0) ? wsum[w - 1] : 0;
        if (i < n) data[i] = (x + woff) - v + carry;
        int ct = chunk_total;
        __syncthreads();
        carry += ct;
    }
}

__global__ void scatter_kernel(const int* __restrict__ ei, const int* __restrict__ flag,
                               int* __restrict__ cursor, int* __restrict__ csr,
                               int* __restrict__ dstv, int E, int Etot) {
    int i = blockIdx.x * 256 + threadIdx.x;
    if (i >= Etot) return;
    int is64 = flag[0];
    int src, dst;
    if (i < E) {
        src = load_idx(ei, is64, i);
        dst = load_idx(ei, is64, (long long)E + i);
    } else {
        src = dst = i - E;
    }
    int pos = atomicAdd(&cursor[dst], 1);
    csr[pos] = src;
    dstv[pos] = dst;
}

// ---------------- fold bias+BN into scale/shift ----------------
__global__ void prep_bn_kernel(const float* b1, const float* g1, const float* bb1,
                               const float* m1, const float* v1,
                               const float* b2, const float* g2, const float* bb2,
                               const float* m2, const float* v2,
                               float* __restrict__ bnsc, float* __restrict__ bnsh) {
    int t = threadIdx.x;
    if (t < 256) {
        float s = g1[t] * rsqrtf(v1[t] + BN_EPS);
        bnsc[t] = s;
        bnsh[t] = (b1[t] - m1[t]) * s + bb1[t];
    } else if (t < 320) {
        int c = t - 256;
        float s = g2[c] * rsqrtf(v2[c] + BN_EPS);
        bnsc[t] = s;
        bnsh[t] = (b2[c] - m2[c]) * s + bb2[c];
    }
}

// ---------------- cast x -> bf16 ----------------
__global__ void castx_kernel(const float* __restrict__ x, ushortt* __restrict__ xb, int n8) {
    int i = blockIdx.x * 256 + threadIdx.x;
    if (i >= n8) return;
    const float4* src = (const float4*)(x + (size_t)i * 8);
    float4 v0 = src[0], v1 = src[1];
    uint4 pk = make_uint4(pack2bf(v0.x, v0.y), pack2bf(v0.z, v0.w),
                          pack2bf(v1.x, v1.y), pack2bf(v1.z, v1.w));
    *(uint4*)(xb + (size_t)i * 8) = pk;
}

// ---------------- W -> bf16 transposed (WT[n][k] = W[k][n], rows >= Norig zero) ----------------
__global__ void prep_wt_kernel(const float* __restrict__ W, ushortt* __restrict__ WT,
                               int K, int Norig, int Npad) {
    int i = blockIdx.x * 256 + threadIdx.x;
    if (i >= K * Npad) return;
    int n = i / K, k = i % K;
    WT[i] = (n < Norig) ? f2bf(W[(size_t)k * Norig + n]) : (ushortt)0;
}

// ---------------- MFMA GEMM (bf16 A [M][K], bf16 WT [Npad][K]) + fused attn dots ----------------
// Block: 256 thr = 4 waves; tile 64 rows x 64 cols; K-loop step 32; 16x16x32 bf16 MFMA.
// L1MODE: head = blockIdx.y, nstride = 256, col base = head*64, a_s/a_d at [m*4+head].
// else:   nstride = 64, a_s[m]/a_d[m]. Attn guard: local col < NCATT.
template <int K, int NCATT, bool L1MODE>
__launch_bounds__(256)
__global__ void gemm_mfma_kernel(const ushortt* __restrict__ A, const ushortt* __restrict__ BT,
                                 ushortt* __restrict__ hB,
                                 const float* __restrict__ atts, const float* __restrict__ attd,
                                 float* __restrict__ a_s, float* __restrict__ a_d, int M) {
    __shared__ ushortt Abuf[64][40];
    __shared__ ushortt Bbuf[64][40];
    int m0 = blockIdx.x * 64;
    int head = L1MODE ? blockIdx.y : 0;
    int n0g = head * 64;                       // global col base (0 for non-L1)
    int t = threadIdx.x;
    int w = t >> 6, l = t & 63;
    int colg = l & 15, kg = l >> 4;
    int srow = t >> 2, sseg = t & 3;           // staging: 4 threads/row

    fx4 acc[4] = {};

    for (int k0 = 0; k0 < K; k0 += 32) {
        // stage A (64 rows x 32 k) and BT (64 cols x 32 k)
        uint4 av = make_uint4(0u, 0u, 0u, 0u);
        if (m0 + srow < M)
            av = *(const uint4*)(A + (size_t)(m0 + srow) * K + k0 + sseg * 8);
        *(uint4*)&Abuf[srow][sseg * 8] = av;
        uint4 bv = *(const uint4*)(BT + (size_t)(n0g + srow) * K + k0 + sseg * 8);
        *(uint4*)&Bbuf[srow][sseg * 8] = bv;
        __syncthreads();
        bf16x8 a = *(const bf16x8*)&Abuf[w * 16 + colg][kg * 8];
        #pragma unroll
        for (int bt = 0; bt < 4; ++bt) {
            bf16x8 b = *(const bf16x8*)&Bbuf[bt * 16 + colg][kg * 8];
            acc[bt] = __builtin_amdgcn_mfma_f32_16x16x32_bf16(a, b, acc[bt], 0, 0, 0);
        }
        __syncthreads();
    }

    // ---- epilogue: bf16 h stores + fused attention dots ----
    // C layout: col = lane&15 (+bt*16), row = kg*4 + reg   [m89-verified]
    const int nstride = L1MODE ? 256 : 64;
    float ps[4] = {}, pd[4] = {};
    #pragma unroll
    for (int bt = 0; bt < 4; ++bt) {
        int cl = bt * 16 + colg;               // local col 0..63
        float as_v = (cl < NCATT) ? atts[n0g + cl] : 0.f;
        float ad_v = (cl < NCATT) ? attd[n0g + cl] : 0.f;
        #pragma unroll
        for (int i = 0; i < 4; ++i) {
            int m = m0 + w * 16 + kg * 4 + i;
            if (m < M)
                hB[(size_t)m * nstride + n0g + cl] = f2bf(acc[bt][i]);
            ps[i] = fmaf(acc[bt][i], as_v, ps[i]);
            pd[i] = fmaf(acc[bt][i], ad_v, pd[i]);
        }
    }
    #pragma unroll
    for (int o = 1; o < 16; o <<= 1) {
        #pragma unroll
        for (int i = 0; i < 4; ++i) {
            ps[i] += __shfl_xor(ps[i], o);
            pd[i] += __shfl_xor(pd[i], o);
        }
    }
    if (colg == 0) {
        #pragma unroll
        for (int i = 0; i < 4; ++i) {
            int m = m0 + w * 16 + kg * 4 + i;
            if (m < M) {
                if constexpr (L1MODE) {
                    a_s[(size_t)m * 4 + head] = ps[i];
                    a_d[(size_t)m * 4 + head] = pd[i];
                } else {
                    a_s[m] = ps[i];
                    a_d[m] = pd[i];
                }
            }
        }
    }
}

// ---------------- alpha layer 1: edge-parallel, 4 heads -> alH[h*Etot + j] fp16 ----------------
__launch_bounds__(256)
__global__ void alpha4e_kernel(const int* __restrict__ csr, const int* __restrict__ dstv,
                               const float* __restrict__ a_s4, const float* __restrict__ a_d4,
                               __half* __restrict__ alH, int Etot) {
    int j = blockIdx.x * 256 + threadIdx.x;
    if (j >= Etot) return;
    int s = csr[j], d = dstv[j];
    fx4 as = *(const fx4*)&a_s4[(size_t)s * 4];
    fx4 ad = *(const fx4*)&a_d4[(size_t)d * 4];
    #pragma unroll
    for (int h = 0; h < 4; ++h) {
        float v = as[h] + ad[h];
        v = v > 0.f ? v : NEG_SLOPE * v;
        alH[(size_t)h * Etot + j] = __float2half(__expf(v));
    }
}

// ---------------- alpha single head: edge-parallel -> alE[j] fp16 ----------------
__launch_bounds__(256)
__global__ void alpha1e_kernel(const int* __restrict__ csr, const int* __restrict__ dstv,
                               const float* __restrict__ a_s, const float* __restrict__ a_d,
                               __half* __restrict__ alE, int Etot) {
    int j = blockIdx.x * 256 + threadIdx.x;
    if (j >= Etot) return;
    float v = a_s[csr[j]] + a_d[dstv[j]];
    v = v > 0.f ? v : NEG_SLOPE * v;
    alE[j] = __float2half(__expf(v));
}

// ---------------- PV layer 1: wave=node, 2 edges/step, 32 lanes/edge, unroll 4 ----------------
__launch_bounds__(256)
__global__ void pv1_kernel(const int* __restrict__ off, const int* __restrict__ csr,
                           const __half* __restrict__ alH, const ushortt* __restrict__ hB,
                           const float* __restrict__ bnsc, const float* __restrict__ bnsh,
                           ushortt* __restrict__ actb, int N, int Etot) {
    int node = blockIdx.x * 4 + (threadIdx.x >> 6);
    int lane = threadIdx.x & 63;
    if (node >= N) return;
    int half = lane >> 5, sub = lane & 31, head = sub >> 3;
    unsigned subb = (unsigned)(sub * 16);
    int beg = off[node], end = off[node + 1], deg = end - beg;
    const __half* alh = alH + (size_t)head * Etot;
    const char* hBb = (const char*)hB;
    float acc[8] = {};
    float ssum = 0.f;
    int nt = (deg + 1) >> 1;
    int j = beg + half;
    int t = 0;
    for (; t + 4 <= nt; t += 4, j += 8) {
        float av[4]; unsigned ro[4];
        #pragma unroll
        for (int q = 0; q < 4; ++q) {
            int jq = j + 2 * q;
            bool v = jq < end;
            int idx = v ? jq : beg;
            int s = csr[idx];
            av[q] = v ? __half2float(alh[idx]) : 0.f;
            ro[q] = (unsigned)s * 512u + subb;
        }
        uint4 h0 = *(const uint4*)(hBb + ro[0]);
        uint4 h1 = *(const uint4*)(hBb + ro[1]);
        uint4 h2 = *(const uint4*)(hBb + ro[2]);
        uint4 h3 = *(const uint4*)(hBb + ro[3]);
        acc8(acc, av[0], h0);
        acc8(acc, av[1], h1);
        acc8(acc, av[2], h2);
        acc8(acc, av[3], h3);
        ssum += (av[0] + av[1]) + (av[2] + av[3]);
    }
    for (; t < nt; ++t, j += 2) {
        bool v = j < end;
        int idx = v ? j : beg;
        int s = csr[idx];
        float a = v ? __half2float(alh[idx]) : 0.f;
        uint4 h = *(const uint4*)(hBb + (unsigned)s * 512u + subb);
        acc8(acc, a, h);
        ssum += a;
    }
    #pragma unroll
    for (int i = 0; i < 8; ++i) acc[i] += __shfl_xor(acc[i], 32);
    ssum += __shfl_xor(ssum, 32);
    if (half == 0) {
        float inv = 1.f / (ssum + 1e-16f);
        int g = sub * 8;
        float o[8];
        #pragma unroll
        for (int i = 0; i < 8; ++i) {
            float v = acc[i] * inv * bnsc[g + i] + bnsh[g + i];
            o[i] = v > 0.f ? v : expm1f(v);
        }
        uint4 pk = make_uint4(pack2bf(o[0], o[1]), pack2bf(o[2], o[3]),
                              pack2bf(o[4], o[5]), pack2bf(o[6], o[7]));
        *(uint4*)&actb[(size_t)node * 256 + g] = pk;
    }
}

// ---------------- PV layer 2: wave=node, 8 lanes/edge, streamed alpha; BN+ELU -> bf16 act2 ----------------
__launch_bounds__(256)
__global__ void pv2_kernel(const int* __restrict__ off, const int* __restrict__ csr,
                           const __half* __restrict__ alE, const ushortt* __restrict__ hB,
                           const float* __restrict__ bnsc, const float* __restrict__ bnsh,
                           ushortt* __restrict__ act2b, int N) {
    int node = blockIdx.x * 4 + (threadIdx.x >> 6);
    int lane = threadIdx.x & 63;
    if (node >= N) return;
    int grp = lane >> 3, sub = lane & 7;
    unsigned subb = (unsigned)(sub * 16);
    int beg = off[node], end = off[node + 1], deg = end - beg;
    const char* hBb = (const char*)hB;
    float acc[8] = {};
    float ssum = 0.f;
    int nt = (deg + 7) >> 3;
    int j = beg + grp;
    int t = 0;
    for (; t + 2 <= nt; t += 2, j += 16) {
        int jA = j, jB = j + 8;
        bool vA = jA < end, vB = jB < end;
        int iA = vA ? jA : beg, iB = vB ? jB : beg;
        int sA = csr[iA], sB = csr[iB];
        float aA = vA ? __half2float(alE[iA]) : 0.f;
        float aB = vB ? __half2float(alE[iB]) : 0.f;
        uint4 hA = *(const uint4*)(hBb + (unsigned)sA * 128u + subb);
        uint4 hBv = *(const uint4*)(hBb + (unsigned)sB * 128u + subb);
        acc8(acc, aA, hA);
        acc8(acc, aB, hBv);
        ssum += aA + aB;
    }
    for (; t < nt; ++t, j += 8) {
        bool v = j < end;
        int idx = v ? j : beg;
        int s = csr[idx];
        float a = v ? __half2float(alE[idx]) : 0.f;
        uint4 h = *(const uint4*)(hBb + (unsigned)s * 128u + subb);
        acc8(acc, a, h);
        ssum += a;
    }
    #pragma unroll
    for (int o = 8; o <= 32; o <<= 1) {
        #pragma unroll
        for (int i = 0; i < 8; ++i) acc[i] += __shfl_xor(acc[i], o);
        ssum += __shfl_xor(ssum, o);
    }
    if (lane < 8) {
        float inv = 1.f / (ssum + 1e-16f);
        int g = lane * 8;
        float o[8];
        #pragma unroll
        for (int i = 0; i < 8; ++i) {
            float v = acc[i] * inv * bnsc[256 + g + i] + bnsh[256 + g + i];
            o[i] = v > 0.f ? v : expm1f(v);
        }
        uint4 pk = make_uint4(pack2bf(o[0], o[1]), pack2bf(o[2], o[3]),
                              pack2bf(o[4], o[5]), pack2bf(o[6], o[7]));
        *(uint4*)&act2b[(size_t)node * 64 + g] = pk;
    }
}

// ---------------- PV layer 3: wave=node, streamed alpha; fused bias + log_softmax -> out ----------------
__launch_bounds__(256)
__global__ void pv3_kernel(const int* __restrict__ off, const int* __restrict__ csr,
                           const __half* __restrict__ alE, const ushortt* __restrict__ hB,
                           const float* __restrict__ bias, float* __restrict__ out, int N) {
    int node = blockIdx.x * 4 + (threadIdx.x >> 6);
    int lane = threadIdx.x & 63;
    if (node >= N) return;
    int grp = lane >> 3, sub = lane & 7;
    unsigned subb = (unsigned)(sub * 16);
    int beg = off[node], end = off[node + 1];
    const char* hBb = (const char*)hB;
    float acc[8] = {};
    float ssum = 0.f;
    for (int j0 = beg; j0 < end; j0 += 8) {
        int j = j0 + grp;
        bool v = j < end;
        int idx = v ? j : beg;
        int s = csr[idx];
        float a = v ? __half2float(alE[idx]) : 0.f;
        uint4 h = *(const uint4*)(hBb + (unsigned)s * 128u + subb);
        acc8(acc, a, h);
        ssum += a;
    }
    #pragma unroll
    for (int o = 8; o <= 32; o <<= 1) {
        #pragma unroll
        for (int i = 0; i < 8; ++i) acc[i] += __shfl_xor(acc[i], o);
        ssum += __shfl_xor(ssum, o);
    }
    float inv = 1.f / (ssum + 1e-16f);
    int g = lane * 8;
    bool act8 = lane < 5;
    float val[8];
    float mx = -INFINITY;
    #pragma unroll
    for (int i = 0; i < 8; ++i) {
        val[i] = act8 ? (acc[i] * inv + bias[act8 ? (g + i) : 0]) : -INFINITY;
        mx = fmaxf(mx, val[i]);
    }
    #pragma unroll
    for (int o = 1; o < 8; o <<= 1) mx = fmaxf(mx, __shfl_xor(mx, o));
    float se = 0.f;
    if (act8) {
        #pragma unroll
        for (int i = 0; i < 8; ++i) se += __expf(val[i] - mx);
    }
    #pragma unroll
    for (int o = 1; o < 8; o <<= 1) se += __shfl_xor(se, o);
    if (act8) {
        float lse = mx + logf(se);
        float* dst = &out[(size_t)node * 40 + g];
        fx4 v0 = {val[0] - lse, val[1] - lse, val[2] - lse, val[3] - lse};
        fx4 v1 = {val[4] - lse, val[5] - lse, val[6] - lse, val[7] - lse};
        *(fx4*)dst = v0;
        *(fx4*)(dst + 4) = v1;
    }
}

// ---------------- host ----------------
extern "C" void kernel_launch(void* const* d_in, const int* in_sizes, int n_in,
                              void* d_out, int out_size, void* d_ws, size_t ws_size,
                              hipStream_t stream) {
    const float* x      = (const float*)d_in[0];
    const int*   ei     = (const int*)d_in[1];
    const float* W1     = (const float*)d_in[2];
    const float* att_s1 = (const float*)d_in[3];
    const float* att_d1 = (const float*)d_in[4];
    const float* b1     = (const float*)d_in[5];
    const float* bn1g   = (const float*)d_in[6];
    const float* bn1b   = (const float*)d_in[7];
    const float* bn1m   = (const float*)d_in[8];
    const float* bn1v   = (const float*)d_in[9];
    const float* W2     = (const float*)d_in[10];
    const float* att_s2 = (const float*)d_in[11];
    const float* att_d2 = (const float*)d_in[12];
    const float* b2     = (const float*)d_in[13];
    const float* bn2g   = (const float*)d_in[14];
    const float* bn2b   = (const float*)d_in[15];
    const float* bn2m   = (const float*)d_in[16];
    const float* bn2v   = (const float*)d_in[17];
    const float* W3     = (const float*)d_in[18];
    const float* att_s3 = (const float*)d_in[19];
    const float* att_d3 = (const float*)d_in[20];
    const float* b3     = (const float*)d_in[21];

    const int N    = in_sizes[0] / IN_DIM;
    const int E    = in_sizes[1] / 2;
    const int Etot = E + N;

    int*   wsi = (int*)d_ws;
    float* wsf = (float*)d_ws;
    size_t p = 0;
    int*   off    = wsi + p; p += (size_t)N + 16;  p = (p + 3) & ~(size_t)3;
    int*   cursor = wsi + p; p += (size_t)N;       p = (p + 3) & ~(size_t)3;
    int*   flag   = wsi + p; p += 16;
    int*   csr    = wsi + p; p += (size_t)Etot;    p = (p + 3) & ~(size_t)3;
    int*   dstv   = wsi + p; p += (size_t)Etot;    p = (p + 3) & ~(size_t)3;
    float* a_s4   = wsf + p; p += (size_t)N * 4;
    float* a_d4   = wsf + p; p += (size_t)N * 4;
    float* bnsc   = wsf + p; p += 384;
    float* bnsh   = wsf + p; p += 384;
    ushortt* xb   = (ushortt*)(wsf + p); p += (size_t)N * 64;   // x bf16 [N][128]
    ushortt* W1T  = (ushortt*)(wsf + p); p += (256 * 128) / 2 + 16;
    ushortt* W2T  = (ushortt*)(wsf + p); p += (64 * 256) / 2 + 16;
    ushortt* W3T  = (ushortt*)(wsf + p); p += (64 * 64) / 2 + 16;
    size_t H = p;            p += (size_t)N * 128;   // hB1 (N*256 bf16) / hB23 (N*64 bf16)
    size_t A1 = p;           p += (size_t)N * 128;   // actb  (N*256 bf16)
    size_t A2 = p;           p += (size_t)N * 32;    // act2b (N*64 bf16)
    __half* alH = (__half*)(wsf + p); p += (size_t)Etot * 2 + 16;  // fp16 alpha (4 heads / reuse)
    if (ws_size < p * 4) return;

    ushortt* hB1   = (ushortt*)(wsf + H);
    ushortt* hB23  = (ushortt*)(wsf + H);
    ushortt* actb  = (ushortt*)(wsf + A1);
    ushortt* act2b = (ushortt*)(wsf + A2);
    __half*  alE   = alH;                            // reuse for layers 2/3

    float* outp = (float*)d_out;

    // ---- CSR build ----
    hipMemsetAsync(off, 0, ((size_t)N + 1) * sizeof(int), stream);
    detect_kernel<<<1, 256, 0, stream>>>((const unsigned int*)ei, flag);
    {
        int blocks = (Etot + 255) / 256;
        hist_kernel<<<blocks, 256, 0, stream>>>(ei, flag, off, E, Etot);
        scan_kernel<<<1, 1024, 0, stream>>>(off, N + 1);
        hipMemcpyAsync(cursor, off, (size_t)N * sizeof(int), hipMemcpyDeviceToDevice, stream);
        scatter_kernel<<<blocks, 256, 0, stream>>>(ei, flag, cursor, csr, dstv, E, Etot);
    }
    prep_bn_kernel<<<1, 384, 0, stream>>>(b1, bn1g, bn1b, bn1m, bn1v,
                                          b2, bn2g, bn2b, bn2m, bn2v, bnsc, bnsh);
    // ---- weight transposes + x cast ----
    prep_wt_kernel<<<(256 * 128 + 255) / 256, 256, 0, stream>>>(W1, W1T, 128, 256, 256);
    prep_wt_kernel<<<(64 * 256 + 255) / 256, 256, 0, stream>>>(W2, W2T, 256, 64, 64);
    prep_wt_kernel<<<(64 * 64 + 255) / 256, 256, 0, stream>>>(W3, W3T, 64, 40, 64);
    castx_kernel<<<((N * 16) + 255) / 256, 256, 0, stream>>>(x, xb, N * 16);

    const int gm64 = (N + 63) / 64;
    const int nb4 = (N + 3) / 4;
    const int eb = (Etot + 255) / 256;

    // ---- layer 1 ----
    gemm_mfma_kernel<128, 64, true>
        <<<dim3(gm64, 4), 256, 0, stream>>>(xb, W1T, hB1, att_s1, att_d1, a_s4, a_d4, N);
    alpha4e_kernel<<<eb, 256, 0, stream>>>(csr, dstv, a_s4, a_d4, alH, Etot);
    pv1_kernel<<<nb4, 256, 0, stream>>>(off, csr, alH, hB1, bnsc, bnsh, actb, N, Etot);

    // ---- layer 2 ----
    gemm_mfma_kernel<256, 64, false>
        <<<dim3(gm64, 1), 256, 0, stream>>>(actb, W2T, hB23, att_s2, att_d2, a_s4, a_d4, N);
    alpha1e_kernel<<<eb, 256, 0, stream>>>(csr, dstv, a_s4, a_d4, alE, Etot);
    pv2_kernel<<<nb4, 256, 0, stream>>>(off, csr, alE, hB23, bnsc, bnsh, act2b, N);

    // ---- layer 3 (log_softmax fused into PV epilogue) ----
    gemm_mfma_kernel<64, 40, false>
        <<<dim3(gm64, 1), 256, 0, stream>>>(act2b, W3T, hB23, att_s3, att_d3, a_s4, a_d4, N);
    alpha1e_kernel<<<eb, 256, 0, stream>>>(csr, dstv, a_s4, a_d4, alE, Etot);
    pv3_kernel<<<nb4, 256, 0, stream>>>(off, csr, alE, hB23, b3, outp, N);
}

// Round 15
// 692.315 us; speedup vs baseline: 1.3255x; 1.0174x over previous
//
#include <hip/hip_runtime.h>
#include <hip/hip_fp16.h>
#include <cstdint>

#define IN_DIM   128
#define HIDC     64
#define HEADS    4
#define OUT_DIM  40
#define NEG_SLOPE 0.2f
#define BN_EPS   1e-5f

typedef unsigned short ushortt;
typedef float fx4 __attribute__((ext_vector_type(4)));
typedef short bf16x8 __attribute__((ext_vector_type(8)));

__device__ __forceinline__ float bfval(ushortt u) {
    return __uint_as_float(((unsigned)u) << 16);
}
__device__ __forceinline__ ushortt f2bf(float f) {
    unsigned u = __float_as_uint(f);
    u += 0x7fffu + ((u >> 16) & 1u);
    return (ushortt)(u >> 16);
}
__device__ __forceinline__ unsigned pack2bf(float a, float b) {
    return (unsigned)f2bf(a) | ((unsigned)f2bf(b) << 16);
}

// acc[0..7] += a * bf16x8(h)
__device__ __forceinline__ void acc8(float* acc, float a, uint4 h) {
    unsigned u;
    u = h.x;
    acc[0] = fmaf(a, __uint_as_float(u << 16), acc[0]);
    acc[1] = fmaf(a, __uint_as_float(u & 0xffff0000u), acc[1]);
    u = h.y;
    acc[2] = fmaf(a, __uint_as_float(u << 16), acc[2]);
    acc[3] = fmaf(a, __uint_as_float(u & 0xffff0000u), acc[3]);
    u = h.z;
    acc[4] = fmaf(a, __uint_as_float(u << 16), acc[4]);
    acc[5] = fmaf(a, __uint_as_float(u & 0xffff0000u), acc[5]);
    u = h.w;
    acc[6] = fmaf(a, __uint_as_float(u << 16), acc[6]);
    acc[7] = fmaf(a, __uint_as_float(u & 0xffff0000u), acc[7]);
}

// ---------------- CSR build ----------------
__global__ void detect_kernel(const unsigned int* __restrict__ e, int* __restrict__ flag) {
    __shared__ int any;
    if (threadIdx.x == 0) any = 0;
    __syncthreads();
    for (int i = threadIdx.x; i < 1024; i += 256)
        if (e[2 * i + 1] != 0u) any = 1;
    __syncthreads();
    if (threadIdx.x == 0) flag[0] = any ? 0 : 1;   // 1 => int64
}

__device__ __forceinline__ int load_idx(const int* ei, int is64, long long pos) {
    return is64 ? ei[2 * pos] : ei[pos];
}

__global__ void hist_kernel(const int* __restrict__ ei, const int* __restrict__ flag,
                            int* __restrict__ deg, int E, int Etot) {
    int i = blockIdx.x * 256 + threadIdx.x;
    if (i >= Etot) return;
    int is64 = flag[0];
    int dst = (i < E) ? load_idx(ei, is64, (long long)E + i) : (i - E);
    atomicAdd(&deg[dst], 1);
}

// exclusive scan in place; also mirrors result into cursor[i] for i < n-1
__global__ void scan_kernel(int* __restrict__ data, int* __restrict__ cursor, int n) {
    __shared__ int wsum[16];
    __shared__ int chunk_total;
    int lane = threadIdx.x & 63;
    int w = threadIdx.x >> 6;
    int carry = 0;
    for (int base = 0; base < n; base += 1024) {
        int i = base + (int)threadIdx.x;
        int v = (i < n) ? data[i] : 0;
        int x = v;
        #pragma unroll
        for (int ofs = 1; ofs < 64; ofs <<= 1) {
            int y = __shfl_up(x, ofs);
            if (lane >= ofs) x += y;
        }
        if (lane == 63) wsum[w] = x;
        __syncthreads();
        if (w == 0) {
            int s = (lane < 16) ? wsum[lane] : 0;
            #pragma unroll
            for (int ofs = 1; ofs < 16; ofs <<= 1) {
                int y = __shfl_up(s, ofs);
                if (lane >= ofs) s += y;
            }
            if (lane < 16) wsum[lane] = s;
            if (lane == 15) chunk_total = s;
        }
        __syncthreads();
        int woff = (w > 0) ? wsum[w - 1] : 0;
        if (i < n) {
            int excl = (x + woff) - v + carry;
            data[i] = excl;
            if (i < n - 1) cursor[i] = excl;
        }
        int ct = chunk_total;
        __syncthreads();
        carry += ct;
    }
}

__global__ void scatter_kernel(const int* __restrict__ ei, const int* __restrict__ flag,
                               int* __restrict__ cursor, int* __restrict__ csr,
                               int* __restrict__ dstv, int E, int Etot) {
    int i = blockIdx.x * 256 + threadIdx.x;
    if (i >= Etot) return;
    int is64 = flag[0];
    int src, dst;
    if (i < E) {
        src = load_idx(ei, is64, i);
        dst = load_idx(ei, is64, (long long)E + i);
    } else {
        src = dst = i - E;
    }
    int pos = atomicAdd(&cursor[dst], 1);
    csr[pos] = src;
    dstv[pos] = dst;
}

// ---------------- one-shot prep: BN fold + three weight transposes (bf16) ----------------
__global__ void prep_all_kernel(const float* b1, const float* g1, const float* bb1,
                                const float* m1, const float* v1,
                                const float* b2, const float* g2, const float* bb2,
                                const float* m2, const float* v2,
                                const float* W1, const float* W2, const float* W3,
                                float* __restrict__ bnsc, float* __restrict__ bnsh,
                                ushortt* __restrict__ W1T, ushortt* __restrict__ W2T,
                                ushortt* __restrict__ W3T) {
    int i = blockIdx.x * 256 + threadIdx.x;
    if (i < 320) {
        if (i < 256) {
            float s = g1[i] * rsqrtf(v1[i] + BN_EPS);
            bnsc[i] = s;
            bnsh[i] = (b1[i] - m1[i]) * s + bb1[i];
        } else {
            int c = i - 256;
            float s = g2[c] * rsqrtf(v2[c] + BN_EPS);
            bnsc[i] = s;
            bnsh[i] = (b2[c] - m2[c]) * s + bb2[c];
        }
        return;
    }
    int j = i - 320;
    if (j < 256 * 128) {                       // W1T[n][k], n<256, k<128
        int n = j >> 7, k = j & 127;
        W1T[j] = f2bf(W1[(size_t)k * 256 + n]);
        return;
    }
    j -= 256 * 128;
    if (j < 64 * 256) {                        // W2T[n][k], n<64, k<256
        int n = j >> 8, k = j & 255;
        W2T[j] = f2bf(W2[(size_t)k * 64 + n]);
        return;
    }
    j -= 64 * 256;
    if (j < 64 * 64) {                         // W3T[n][k], n<64 (pad>=40), k<64
        int n = j >> 6, k = j & 63;
        W3T[j] = (n < OUT_DIM) ? f2bf(W3[(size_t)k * OUT_DIM + n]) : (ushortt)0;
    }
}

// ---------------- MFMA GEMM layer 1: fp32 A [M][128] x W1T bf16 [256][128], 64x256 tile ----------------
// 4 waves; wave w owns rows w*16..w*16+15, all 256 cols (16 col-frags).
// Fused: bf16 h store + per-head attention dots.
__launch_bounds__(256)
__global__ void gemm1_mfma_kernel(const float* __restrict__ x, const ushortt* __restrict__ BT,
                                  ushortt* __restrict__ hB,
                                  const float* __restrict__ atts, const float* __restrict__ attd,
                                  float* __restrict__ a_s4, float* __restrict__ a_d4, int M) {
    __shared__ ushortt Abuf[64][40];
    __shared__ ushortt Bbuf[256][40];
    int m0 = blockIdx.x * 64;
    int t = threadIdx.x;
    int w = t >> 6, l = t & 63;
    int colg = l & 15, kg = l >> 4;
    int srow = t >> 2, sseg = t & 3;

    fx4 acc[16] = {};

    for (int k0 = 0; k0 < 128; k0 += 32) {
        // stage A: fp32 -> bf16 convert (64 rows x 32 k)
        float4 v0 = make_float4(0.f, 0.f, 0.f, 0.f), v1 = v0;
        if (m0 + srow < M) {
            const float4* sp = (const float4*)(x + (size_t)(m0 + srow) * 128 + k0 + sseg * 8);
            v0 = sp[0]; v1 = sp[1];
        }
        *(uint4*)&Abuf[srow][sseg * 8] = make_uint4(pack2bf(v0.x, v0.y), pack2bf(v0.z, v0.w),
                                                    pack2bf(v1.x, v1.y), pack2bf(v1.z, v1.w));
        // stage B: 256 cols x 32 k (thread t = col t)
        #pragma unroll
        for (int seg = 0; seg < 4; ++seg)
            *(uint4*)&Bbuf[t][seg * 8] = *(const uint4*)(BT + (size_t)t * 128 + k0 + seg * 8);
        __syncthreads();
        bf16x8 a = *(const bf16x8*)&Abuf[w * 16 + colg][kg * 8];
        #pragma unroll
        for (int ct = 0; ct < 16; ++ct) {
            bf16x8 b = *(const bf16x8*)&Bbuf[ct * 16 + colg][kg * 8];
            acc[ct] = __builtin_amdgcn_mfma_f32_16x16x32_bf16(a, b, acc[ct], 0, 0, 0);
        }
        __syncthreads();
    }

    // ---- epilogue: h stores + per-head attn dots (C: col=colg(+ct*16), row=kg*4+i) ----
    float ps[4][4] = {}, pd[4][4] = {};
    #pragma unroll
    for (int ct = 0; ct < 16; ++ct) {
        int cl = ct * 16 + colg;
        int h = cl >> 6;
        float as_v = atts[cl], ad_v = attd[cl];
        #pragma unroll
        for (int i = 0; i < 4; ++i) {
            int m = m0 + w * 16 + kg * 4 + i;
            if (m < M)
                hB[(size_t)m * 256 + cl] = f2bf(acc[ct][i]);
            ps[i][h] = fmaf(acc[ct][i], as_v, ps[i][h]);
            pd[i][h] = fmaf(acc[ct][i], ad_v, pd[i][h]);
        }
    }
    #pragma unroll
    for (int o = 1; o < 16; o <<= 1) {
        #pragma unroll
        for (int i = 0; i < 4; ++i)
            #pragma unroll
            for (int h = 0; h < 4; ++h) {
                ps[i][h] += __shfl_xor(ps[i][h], o);
                pd[i][h] += __shfl_xor(pd[i][h], o);
            }
    }
    if (colg == 0) {
        #pragma unroll
        for (int i = 0; i < 4; ++i) {
            int m = m0 + w * 16 + kg * 4 + i;
            if (m < M) {
                #pragma unroll
                for (int h = 0; h < 4; ++h) {
                    a_s4[(size_t)m * 4 + h] = ps[i][h];
                    a_d4[(size_t)m * 4 + h] = pd[i][h];
                }
            }
        }
    }
}

// ---------------- MFMA GEMM layers 2/3 (bf16 A [M][K], bf16 WT [64][K]) + fused attn dots ----------------
template <int K, int NCATT>
__launch_bounds__(256)
__global__ void gemm_mfma_kernel(const ushortt* __restrict__ A, const ushortt* __restrict__ BT,
                                 ushortt* __restrict__ hB,
                                 const float* __restrict__ atts, const float* __restrict__ attd,
                                 float* __restrict__ a_s, float* __restrict__ a_d, int M) {
    __shared__ ushortt Abuf[64][40];
    __shared__ ushortt Bbuf[64][40];
    int m0 = blockIdx.x * 64;
    int t = threadIdx.x;
    int w = t >> 6, l = t & 63;
    int colg = l & 15, kg = l >> 4;
    int srow = t >> 2, sseg = t & 3;

    fx4 acc[4] = {};

    for (int k0 = 0; k0 < K; k0 += 32) {
        uint4 av = make_uint4(0u, 0u, 0u, 0u);
        if (m0 + srow < M)
            av = *(const uint4*)(A + (size_t)(m0 + srow) * K + k0 + sseg * 8);
        *(uint4*)&Abuf[srow][sseg * 8] = av;
        uint4 bv = *(const uint4*)(BT + (size_t)srow * K + k0 + sseg * 8);
        *(uint4*)&Bbuf[srow][sseg * 8] = bv;
        __syncthreads();
        bf16x8 a = *(const bf16x8*)&Abuf[w * 16 + colg][kg * 8];
        #pragma unroll
        for (int bt = 0; bt < 4; ++bt) {
            bf16x8 b = *(const bf16x8*)&Bbuf[bt * 16 + colg][kg * 8];
            acc[bt] = __builtin_amdgcn_mfma_f32_16x16x32_bf16(a, b, acc[bt], 0, 0, 0);
        }
        __syncthreads();
    }

    float ps[4] = {}, pd[4] = {};
    #pragma unroll
    for (int bt = 0; bt < 4; ++bt) {
        int cl = bt * 16 + colg;
        float as_v = (cl < NCATT) ? atts[cl] : 0.f;
        float ad_v = (cl < NCATT) ? attd[cl] : 0.f;
        #pragma unroll
        for (int i = 0; i < 4; ++i) {
            int m = m0 + w * 16 + kg * 4 + i;
            if (m < M)
                hB[(size_t)m * 64 + cl] = f2bf(acc[bt][i]);
            ps[i] = fmaf(acc[bt][i], as_v, ps[i]);
            pd[i] = fmaf(acc[bt][i], ad_v, pd[i]);
        }
    }
    #pragma unroll
    for (int o = 1; o < 16; o <<= 1) {
        #pragma unroll
        for (int i = 0; i < 4; ++i) {
            ps[i] += __shfl_xor(ps[i], o);
            pd[i] += __shfl_xor(pd[i], o);
        }
    }
    if (colg == 0) {
        #pragma unroll
        for (int i = 0; i < 4; ++i) {
            int m = m0 + w * 16 + kg * 4 + i;
            if (m < M) { a_s[m] = ps[i]; a_d[m] = pd[i]; }
        }
    }
}

// ---------------- alpha layer 1: edge-parallel, 4 heads -> alH[h*Etot + j] fp16 ----------------
__launch_bounds__(256)
__global__ void alpha4e_kernel(const int* __restrict__ csr, const int* __restrict__ dstv,
                               const float* __restrict__ a_s4, const float* __restrict__ a_d4,
                               __half* __restrict__ alH, int Etot) {
    int j = blockIdx.x * 256 + threadIdx.x;
    if (j >= Etot) return;
    int s = csr[j], d = dstv[j];
    fx4 as = *(const fx4*)&a_s4[(size_t)s * 4];
    fx4 ad = *(const fx4*)&a_d4[(size_t)d * 4];
    #pragma unroll
    for (int h = 0; h < 4; ++h) {
        float v = as[h] + ad[h];
        v = v > 0.f ? v : NEG_SLOPE * v;
        alH[(size_t)h * Etot + j] = __float2half(__expf(v));
    }
}

// ---------------- alpha single head: edge-parallel -> alE[j] fp16 ----------------
__launch_bounds__(256)
__global__ void alpha1e_kernel(const int* __restrict__ csr, const int* __restrict__ dstv,
                               const float* __restrict__ a_s, const float* __restrict__ a_d,
                               __half* __restrict__ alE, int Etot) {
    int j = blockIdx.x * 256 + threadIdx.x;
    if (j >= Etot) return;
    float v = a_s[csr[j]] + a_d[dstv[j]];
    v = v > 0.f ? v : NEG_SLOPE * v;
    alE[j] = __float2half(__expf(v));
}

// ---------------- PV layer 1: wave=node, 2 edges/step, 32 lanes/edge, unroll 4 ----------------
__launch_bounds__(256)
__global__ void pv1_kernel(const int* __restrict__ off, const int* __restrict__ csr,
                           const __half* __restrict__ alH, const ushortt* __restrict__ hB,
                           const float* __restrict__ bnsc, const float* __restrict__ bnsh,
                           ushortt* __restrict__ actb, int N, int Etot) {
    int node = blockIdx.x * 4 + (threadIdx.x >> 6);
    int lane = threadIdx.x & 63;
    if (node >= N) return;
    int half = lane >> 5, sub = lane & 31, head = sub >> 3;
    unsigned subb = (unsigned)(sub * 16);
    int beg = off[node], end = off[node + 1], deg = end - beg;
    const __half* alh = alH + (size_t)head * Etot;
    const char* hBb = (const char*)hB;
    float acc[8] = {};
    float ssum = 0.f;
    int nt = (deg + 1) >> 1;
    int j = beg + half;
    int t = 0;
    for (; t + 4 <= nt; t += 4, j += 8) {
        float av[4]; unsigned ro[4];
        #pragma unroll
        for (int q = 0; q < 4; ++q) {
            int jq = j + 2 * q;
            bool v = jq < end;
            int idx = v ? jq : beg;
            int s = csr[idx];
            av[q] = v ? __half2float(alh[idx]) : 0.f;
            ro[q] = (unsigned)s * 512u + subb;
        }
        uint4 h0 = *(const uint4*)(hBb + ro[0]);
        uint4 h1 = *(const uint4*)(hBb + ro[1]);
        uint4 h2 = *(const uint4*)(hBb + ro[2]);
        uint4 h3 = *(const uint4*)(hBb + ro[3]);
        acc8(acc, av[0], h0);
        acc8(acc, av[1], h1);
        acc8(acc, av[2], h2);
        acc8(acc, av[3], h3);
        ssum += (av[0] + av[1]) + (av[2] + av[3]);
    }
    for (; t < nt; ++t, j += 2) {
        bool v = j < end;
        int idx = v ? j : beg;
        int s = csr[idx];
        float a = v ? __half2float(alh[idx]) : 0.f;
        uint4 h = *(const uint4*)(hBb + (unsigned)s * 512u + subb);
        acc8(acc, a, h);
        ssum += a;
    }
    #pragma unroll
    for (int i = 0; i < 8; ++i) acc[i] += __shfl_xor(acc[i], 32);
    ssum += __shfl_xor(ssum, 32);
    if (half == 0) {
        float inv = 1.f / (ssum + 1e-16f);
        int g = sub * 8;
        float o[8];
        #pragma unroll
        for (int i = 0; i < 8; ++i) {
            float v = acc[i] * inv * bnsc[g + i] + bnsh[g + i];
            o[i] = v > 0.f ? v : expm1f(v);
        }
        uint4 pk = make_uint4(pack2bf(o[0], o[1]), pack2bf(o[2], o[3]),
                              pack2bf(o[4], o[5]), pack2bf(o[6], o[7]));
        *(uint4*)&actb[(size_t)node * 256 + g] = pk;
    }
}

// ---------------- PV layer 2: wave=node, 8 lanes/edge, streamed alpha; BN+ELU -> bf16 act2 ----------------
__launch_bounds__(256)
__global__ void pv2_kernel(const int* __restrict__ off, const int* __restrict__ csr,
                           const __half* __restrict__ alE, const ushortt* __restrict__ hB,
                           const float* __restrict__ bnsc, const float* __restrict__ bnsh,
                           ushortt* __restrict__ act2b, int N) {
    int node = blockIdx.x * 4 + (threadIdx.x >> 6);
    int lane = threadIdx.x & 63;
    if (node >= N) return;
    int grp = lane >> 3, sub = lane & 7;
    unsigned subb = (unsigned)(sub * 16);
    int beg = off[node], end = off[node + 1], deg = end - beg;
    const char* hBb = (const char*)hB;
    float acc[8] = {};
    float ssum = 0.f;
    int nt = (deg + 7) >> 3;
    int j = beg + grp;
    int t = 0;
    for (; t + 2 <= nt; t += 2, j += 16) {
        int jA = j, jB = j + 8;
        bool vA = jA < end, vB = jB < end;
        int iA = vA ? jA : beg, iB = vB ? jB : beg;
        int sA = csr[iA], sB = csr[iB];
        float aA = vA ? __half2float(alE[iA]) : 0.f;
        float aB = vB ? __half2float(alE[iB]) : 0.f;
        uint4 hA = *(const uint4*)(hBb + (unsigned)sA * 128u + subb);
        uint4 hBv = *(const uint4*)(hBb + (unsigned)sB * 128u + subb);
        acc8(acc, aA, hA);
        acc8(acc, aB, hBv);
        ssum += aA + aB;
    }
    for (; t < nt; ++t, j += 8) {
        bool v = j < end;
        int idx = v ? j : beg;
        int s = csr[idx];
        float a = v ? __half2float(alE[idx]) : 0.f;
        uint4 h = *(const uint4*)(hBb + (unsigned)s * 128u + subb);
        acc8(acc, a, h);
        ssum += a;
    }
    #pragma unroll
    for (int o = 8; o <= 32; o <<= 1) {
        #pragma unroll
        for (int i = 0; i < 8; ++i) acc[i] += __shfl_xor(acc[i], o);
        ssum += __shfl_xor(ssum, o);
    }
    if (lane < 8) {
        float inv = 1.f / (ssum + 1e-16f);
        int g = lane * 8;
        float o[8];
        #pragma unroll
        for (int i = 0; i < 8; ++i) {
            float v = acc[i] * inv * bnsc[256 + g + i] + bnsh[256 + g + i];
            o[i] = v > 0.f ? v : expm1f(v);
        }
        uint4 pk = make_uint4(pack2bf(o[0], o[1]), pack2bf(o[2], o[3]),
                              pack2bf(o[4], o[5]), pack2bf(o[6], o[7]));
        *(uint4*)&act2b[(size_t)node * 64 + g] = pk;
    }
}

// ---------------- PV layer 3: wave=node, streamed alpha; fused bias + log_softmax -> out ----------------
__launch_bounds__(256)
__global__ void pv3_kernel(const int* __restrict__ off, const int* __restrict__ csr,
                           const __half* __restrict__ alE, const ushortt* __restrict__ hB,
                           const float* __restrict__ bias, float* __restrict__ out, int N) {
    int node = blockIdx.x * 4 + (threadIdx.x >> 6);
    int lane = threadIdx.x & 63;
    if (node >= N) return;
    int grp = lane >> 3, sub = lane & 7;
    unsigned subb = (unsigned)(sub * 16);
    int beg = off[node], end = off[node + 1];
    const char* hBb = (const char*)hB;
    float acc[8] = {};
    float ssum = 0.f;
    for (int j0 = beg; j0 < end; j0 += 8) {
        int j = j0 + grp;
        bool v = j < end;
        int idx = v ? j : beg;
        int s = csr[idx];
        float a = v ? __half2float(alE[idx]) : 0.f;
        uint4 h = *(const uint4*)(hBb + (unsigned)s * 128u + subb);
        acc8(acc, a, h);
        ssum += a;
    }
    #pragma unroll
    for (int o = 8; o <= 32; o <<= 1) {
        #pragma unroll
        for (int i = 0; i < 8; ++i) acc[i] += __shfl_xor(acc[i], o);
        ssum += __shfl_xor(ssum, o);
    }
    float inv = 1.f / (ssum + 1e-16f);
    int g = lane * 8;
    bool act8 = lane < 5;
    float val[8];
    float mx = -INFINITY;
    #pragma unroll
    for (int i = 0; i < 8; ++i) {
        val[i] = act8 ? (acc[i] * inv + bias[act8 ? (g + i) : 0]) : -INFINITY;
        mx = fmaxf(mx, val[i]);
    }
    #pragma unroll
    for (int o = 1; o < 8; o <<= 1) mx = fmaxf(mx, __shfl_xor(mx, o));
    float se = 0.f;
    if (act8) {
        #pragma unroll
        for (int i = 0; i < 8; ++i) se += __expf(val[i] - mx);
    }
    #pragma unroll
    for (int o = 1; o < 8; o <<= 1) se += __shfl_xor(se, o);
    if (act8) {
        float lse = mx + logf(se);
        float* dst = &out[(size_t)node * 40 + g];
        fx4 v0 = {val[0] - lse, val[1] - lse, val[2] - lse, val[3] - lse};
        fx4 v1 = {val[4] - lse, val[5] - lse, val[6] - lse, val[7] - lse};
        *(fx4*)dst = v0;
        *(fx4*)(dst + 4) = v1;
    }
}

// ---------------- host ----------------
extern "C" void kernel_launch(void* const* d_in, const int* in_sizes, int n_in,
                              void* d_out, int out_size, void* d_ws, size_t ws_size,
                              hipStream_t stream) {
    const float* x      = (const float*)d_in[0];
    const int*   ei     = (const int*)d_in[1];
    const float* W1     = (const float*)d_in[2];
    const float* att_s1 = (const float*)d_in[3];
    const float* att_d1 = (const float*)d_in[4];
    const float* b1     = (const float*)d_in[5];
    const float* bn1g   = (const float*)d_in[6];
    const float* bn1b   = (const float*)d_in[7];
    const float* bn1m   = (const float*)d_in[8];
    const float* bn1v   = (const float*)d_in[9];
    const float* W2     = (const float*)d_in[10];
    const float* att_s2 = (const float*)d_in[11];
    const float* att_d2 = (const float*)d_in[12];
    const float* b2     = (const float*)d_in[13];
    const float* bn2g   = (const float*)d_in[14];
    const float* bn2b   = (const float*)d_in[15];
    const float* bn2m   = (const float*)d_in[16];
    const float* bn2v   = (const float*)d_in[17];
    const float* W3     = (const float*)d_in[18];
    const float* att_s3 = (const float*)d_in[19];
    const float* att_d3 = (const float*)d_in[20];
    const float* b3     = (const float*)d_in[21];

    const int N    = in_sizes[0] / IN_DIM;
    const int E    = in_sizes[1] / 2;
    const int Etot = E + N;

    int*   wsi = (int*)d_ws;
    float* wsf = (float*)d_ws;
    size_t p = 0;
    int*   off    = wsi + p; p += (size_t)N + 16;  p = (p + 3) & ~(size_t)3;
    int*   cursor = wsi + p; p += (size_t)N;       p = (p + 3) & ~(size_t)3;
    int*   flag   = wsi + p; p += 16;
    int*   csr    = wsi + p; p += (size_t)Etot;    p = (p + 3) & ~(size_t)3;
    int*   dstv   = wsi + p; p += (size_t)Etot;    p = (p + 3) & ~(size_t)3;
    float* a_s4   = wsf + p; p += (size_t)N * 4;
    float* a_d4   = wsf + p; p += (size_t)N * 4;
    float* bnsc   = wsf + p; p += 384;
    float* bnsh   = wsf + p; p += 384;
    size_t H = p;            p += (size_t)N * 128;   // hB1 (N*256 bf16) / hB23 (N*64 bf16)
    size_t A1 = p;           p += (size_t)N * 128;   // actb  (N*256 bf16)
    size_t A2 = p;           p += (size_t)N * 32;    // act2b (N*64 bf16)
    __half* alH = (__half*)(wsf + p); p += (size_t)Etot * 2 + 16;  // fp16 alpha (4 heads / reuse)
    ushortt* W1T = (ushortt*)(wsf + p); p += (256 * 128) / 2 + 16;
    ushortt* W2T = (ushortt*)(wsf + p); p += (64 * 256) / 2 + 16;
    ushortt* W3T = (ushortt*)(wsf + p); p += (64 * 64) / 2 + 16;
    if (ws_size < p * 4) return;

    ushortt* hB1   = (ushortt*)(wsf + H);
    ushortt* hB23  = (ushortt*)(wsf + H);
    ushortt* actb  = (ushortt*)(wsf + A1);
    ushortt* act2b = (ushortt*)(wsf + A2);
    __half*  alE   = alH;

    float* outp = (float*)d_out;

    // ---- CSR build + prep ----
    hipMemsetAsync(off, 0, ((size_t)N + 1) * sizeof(int), stream);
    detect_kernel<<<1, 256, 0, stream>>>((const unsigned int*)ei, flag);
    {
        int blocks = (Etot + 255) / 256;
        hist_kernel<<<blocks, 256, 0, stream>>>(ei, flag, off, E, Etot);
        scan_kernel<<<1, 1024, 0, stream>>>(off, cursor, N + 1);
        scatter_kernel<<<blocks, 256, 0, stream>>>(ei, flag, cursor, csr, dstv, E, Etot);
    }
    {
        int total = 320 + 256 * 128 + 64 * 256 + 64 * 64;
        prep_all_kernel<<<(total + 255) / 256, 256, 0, stream>>>(
            b1, bn1g, bn1b, bn1m, bn1v, b2, bn2g, bn2b, bn2m, bn2v,
            W1, W2, W3, bnsc, bnsh, W1T, W2T, W3T);
    }

    const int gm64 = (N + 63) / 64;
    const int nb4 = (N + 3) / 4;
    const int eb = (Etot + 255) / 256;

    // ---- layer 1 ----
    gemm1_mfma_kernel<<<gm64, 256, 0, stream>>>(x, W1T, hB1, att_s1, att_d1, a_s4, a_d4, N);
    alpha4e_kernel<<<eb, 256, 0, stream>>>(csr, dstv, a_s4, a_d4, alH, Etot);
    pv1_kernel<<<nb4, 256, 0, stream>>>(off, csr, alH, hB1, bnsc, bnsh, actb, N, Etot);

    // ---- layer 2 ----
    gemm_mfma_kernel<256, 64><<<gm64, 256, 0, stream>>>(actb, W2T, hB23, att_s2, att_d2,
                                                        a_s4, a_d4, N);
    alpha1e_kernel<<<eb, 256, 0, stream>>>(csr, dstv, a_s4, a_d4, alE, Etot);
    pv2_kernel<<<nb4, 256, 0, stream>>>(off, csr, alE, hB23, bnsc, bnsh, act2b, N);

    // ---- layer 3 (log_softmax fused into PV epilogue) ----
    gemm_mfma_kernel<64, 40><<<gm64, 256, 0, stream>>>(act2b, W3T, hB23, att_s3, att_d3,
                                                       a_s4, a_d4, N);
    alpha1e_kernel<<<eb, 256, 0, stream>>>(csr, dstv, a_s4, a_d4, alE, Etot);
    pv3_kernel<<<nb4, 256, 0, stream>>>(off, csr, alE, hB23, b3, outp, N);
}

// Round 16
// 668.036 us; speedup vs baseline: 1.3736x; 1.0363x over previous
//
#include <hip/hip_runtime.h>
#include <hip/hip_fp16.h>
#include <cstdint>

#define IN_DIM   128
#define HIDC     64
#define HEADS    4
#define OUT_DIM  40
#define NEG_SLOPE 0.2f
#define BN_EPS   1e-5f

typedef unsigned short ushortt;
typedef float fx4 __attribute__((ext_vector_type(4)));
typedef short bf16x8 __attribute__((ext_vector_type(8)));

__device__ __forceinline__ float bfval(ushortt u) {
    return __uint_as_float(((unsigned)u) << 16);
}
__device__ __forceinline__ ushortt f2bf(float f) {
    unsigned u = __float_as_uint(f);
    u += 0x7fffu + ((u >> 16) & 1u);
    return (ushortt)(u >> 16);
}
__device__ __forceinline__ unsigned pack2bf(float a, float b) {
    return (unsigned)f2bf(a) | ((unsigned)f2bf(b) << 16);
}

// acc[0..7] += a * bf16x8(h)
__device__ __forceinline__ void acc8(float* acc, float a, uint4 h) {
    unsigned u;
    u = h.x;
    acc[0] = fmaf(a, __uint_as_float(u << 16), acc[0]);
    acc[1] = fmaf(a, __uint_as_float(u & 0xffff0000u), acc[1]);
    u = h.y;
    acc[2] = fmaf(a, __uint_as_float(u << 16), acc[2]);
    acc[3] = fmaf(a, __uint_as_float(u & 0xffff0000u), acc[3]);
    u = h.z;
    acc[4] = fmaf(a, __uint_as_float(u << 16), acc[4]);
    acc[5] = fmaf(a, __uint_as_float(u & 0xffff0000u), acc[5]);
    u = h.w;
    acc[6] = fmaf(a, __uint_as_float(u << 16), acc[6]);
    acc[7] = fmaf(a, __uint_as_float(u & 0xffff0000u), acc[7]);
}

// ---------------- CSR build ----------------
__global__ void detect_kernel(const unsigned int* __restrict__ e, int* __restrict__ flag) {
    __shared__ int any;
    if (threadIdx.x == 0) any = 0;
    __syncthreads();
    for (int i = threadIdx.x; i < 1024; i += 256)
        if (e[2 * i + 1] != 0u) any = 1;
    __syncthreads();
    if (threadIdx.x == 0) flag[0] = any ? 0 : 1;   // 1 => int64
}

__device__ __forceinline__ int load_idx(const int* ei, int is64, long long pos) {
    return is64 ? ei[2 * pos] : ei[pos];
}

__global__ void hist_kernel(const int* __restrict__ ei, const int* __restrict__ flag,
                            int* __restrict__ deg, int E, int Etot) {
    int i = blockIdx.x * 256 + threadIdx.x;
    if (i >= Etot) return;
    int is64 = flag[0];
    int dst = (i < E) ? load_idx(ei, is64, (long long)E + i) : (i - E);
    atomicAdd(&deg[dst], 1);
}

// exclusive scan in place (single block, 1024 thr, 4 elems/thr); mirrors into cursor[i], i<n-1
__global__ void scan_kernel(int* __restrict__ data, int* __restrict__ cursor, int n) {
    __shared__ int wsum[16];
    __shared__ int chunk_total;
    int lane = threadIdx.x & 63;
    int w = threadIdx.x >> 6;
    int carry = 0;
    for (int base = 0; base < n; base += 4096) {
        int i4 = base + (int)threadIdx.x * 4;
        int d0 = 0, d1 = 0, d2 = 0, d3 = 0;
        if (i4 + 3 < n) {
            int4 v = *(const int4*)&data[i4];
            d0 = v.x; d1 = v.y; d2 = v.z; d3 = v.w;
        } else {
            if (i4 + 0 < n) d0 = data[i4 + 0];
            if (i4 + 1 < n) d1 = data[i4 + 1];
            if (i4 + 2 < n) d2 = data[i4 + 2];
            if (i4 + 3 < n) d3 = data[i4 + 3];
        }
        int tsum = d0 + d1 + d2 + d3;
        int x = tsum;
        #pragma unroll
        for (int ofs = 1; ofs < 64; ofs <<= 1) {
            int y = __shfl_up(x, ofs);
            if (lane >= ofs) x += y;
        }
        if (lane == 63) wsum[w] = x;
        __syncthreads();
        if (w == 0) {
            int s = (lane < 16) ? wsum[lane] : 0;
            #pragma unroll
            for (int ofs = 1; ofs < 16; ofs <<= 1) {
                int y = __shfl_up(s, ofs);
                if (lane >= ofs) s += y;
            }
            if (lane < 16) wsum[lane] = s;
            if (lane == 15) chunk_total = s;
        }
        __syncthreads();
        int woff = (w > 0) ? wsum[w - 1] : 0;
        int e0 = (x - tsum) + woff + carry;
        int e1 = e0 + d0, e2 = e1 + d1, e3 = e2 + d2;
        if (i4 + 3 < n) {
            *(int4*)&data[i4] = make_int4(e0, e1, e2, e3);
        } else {
            if (i4 + 0 < n) data[i4 + 0] = e0;
            if (i4 + 1 < n) data[i4 + 1] = e1;
            if (i4 + 2 < n) data[i4 + 2] = e2;
            if (i4 + 3 < n) data[i4 + 3] = e3;
        }
        if (i4 + 0 < n - 1) cursor[i4 + 0] = e0;
        if (i4 + 1 < n - 1) cursor[i4 + 1] = e1;
        if (i4 + 2 < n - 1) cursor[i4 + 2] = e2;
        if (i4 + 3 < n - 1) cursor[i4 + 3] = e3;
        int ct = chunk_total;
        __syncthreads();
        carry += ct;
    }
}

// dstv[j] = node for j in [off[node], off[node+1]) — sequential coalesced writes
__global__ void fill_dstv_kernel(const int* __restrict__ off, int* __restrict__ dstv, int N) {
    int node = blockIdx.x * 4 + (threadIdx.x >> 6);
    int lane = threadIdx.x & 63;
    if (node >= N) return;
    int beg = off[node], end = off[node + 1];
    for (int j = beg + lane; j < end; j += 64) dstv[j] = node;
}

__global__ void scatter_kernel(const int* __restrict__ ei, const int* __restrict__ flag,
                               int* __restrict__ cursor, int* __restrict__ csr,
                               int E, int Etot) {
    int i = blockIdx.x * 256 + threadIdx.x;
    if (i >= Etot) return;
    int is64 = flag[0];
    int src, dst;
    if (i < E) {
        src = load_idx(ei, is64, i);
        dst = load_idx(ei, is64, (long long)E + i);
    } else {
        src = dst = i - E;
    }
    int pos = atomicAdd(&cursor[dst], 1);
    csr[pos] = src;
}

// ---------------- one-shot prep: BN fold + three weight transposes (bf16) ----------------
__global__ void prep_all_kernel(const float* b1, const float* g1, const float* bb1,
                                const float* m1, const float* v1,
                                const float* b2, const float* g2, const float* bb2,
                                const float* m2, const float* v2,
                                const float* W1, const float* W2, const float* W3,
                                float* __restrict__ bnsc, float* __restrict__ bnsh,
                                ushortt* __restrict__ W1T, ushortt* __restrict__ W2T,
                                ushortt* __restrict__ W3T) {
    int i = blockIdx.x * 256 + threadIdx.x;
    if (i < 320) {
        if (i < 256) {
            float s = g1[i] * rsqrtf(v1[i] + BN_EPS);
            bnsc[i] = s;
            bnsh[i] = (b1[i] - m1[i]) * s + bb1[i];
        } else {
            int c = i - 256;
            float s = g2[c] * rsqrtf(v2[c] + BN_EPS);
            bnsc[i] = s;
            bnsh[i] = (b2[c] - m2[c]) * s + bb2[c];
        }
        return;
    }
    int j = i - 320;
    if (j < 256 * 128) {                       // W1T[n][k]
        int n = j >> 7, k = j & 127;
        W1T[j] = f2bf(W1[(size_t)k * 256 + n]);
        return;
    }
    j -= 256 * 128;
    if (j < 64 * 256) {                        // W2T[n][k]
        int n = j >> 8, k = j & 255;
        W2T[j] = f2bf(W2[(size_t)k * 64 + n]);
        return;
    }
    j -= 64 * 256;
    if (j < 64 * 64) {                         // W3T[n][k] (pad rows >= 40 zero)
        int n = j >> 6, k = j & 63;
        W3T[j] = (n < OUT_DIM) ? f2bf(W3[(size_t)k * OUT_DIM + n]) : (ushortt)0;
    }
}

// ---------------- MFMA GEMM layer 1: fp32 A [M][128] x W1T bf16 [256][128], 64x256 tile ----------------
__launch_bounds__(256)
__global__ void gemm1_mfma_kernel(const float* __restrict__ x, const ushortt* __restrict__ BT,
                                  ushortt* __restrict__ hB,
                                  const float* __restrict__ atts, const float* __restrict__ attd,
                                  float* __restrict__ a_s4, float* __restrict__ a_d4, int M) {
    __shared__ ushortt Abuf[64][40];
    __shared__ ushortt Bbuf[256][40];
    int m0 = blockIdx.x * 64;
    int t = threadIdx.x;
    int w = t >> 6, l = t & 63;
    int colg = l & 15, kg = l >> 4;
    int srow = t >> 2, sseg = t & 3;

    fx4 acc[16] = {};

    for (int k0 = 0; k0 < 128; k0 += 32) {
        float4 v0 = make_float4(0.f, 0.f, 0.f, 0.f), v1 = v0;
        if (m0 + srow < M) {
            const float4* sp = (const float4*)(x + (size_t)(m0 + srow) * 128 + k0 + sseg * 8);
            v0 = sp[0]; v1 = sp[1];
        }
        *(uint4*)&Abuf[srow][sseg * 8] = make_uint4(pack2bf(v0.x, v0.y), pack2bf(v0.z, v0.w),
                                                    pack2bf(v1.x, v1.y), pack2bf(v1.z, v1.w));
        #pragma unroll
        for (int seg = 0; seg < 4; ++seg)
            *(uint4*)&Bbuf[t][seg * 8] = *(const uint4*)(BT + (size_t)t * 128 + k0 + seg * 8);
        __syncthreads();
        bf16x8 a = *(const bf16x8*)&Abuf[w * 16 + colg][kg * 8];
        #pragma unroll
        for (int ct = 0; ct < 16; ++ct) {
            bf16x8 b = *(const bf16x8*)&Bbuf[ct * 16 + colg][kg * 8];
            acc[ct] = __builtin_amdgcn_mfma_f32_16x16x32_bf16(a, b, acc[ct], 0, 0, 0);
        }
        __syncthreads();
    }

    float ps[4][4] = {}, pd[4][4] = {};
    #pragma unroll
    for (int ct = 0; ct < 16; ++ct) {
        int cl = ct * 16 + colg;
        int h = cl >> 6;
        float as_v = atts[cl], ad_v = attd[cl];
        #pragma unroll
        for (int i = 0; i < 4; ++i) {
            int m = m0 + w * 16 + kg * 4 + i;
            if (m < M)
                hB[(size_t)m * 256 + cl] = f2bf(acc[ct][i]);
            ps[i][h] = fmaf(acc[ct][i], as_v, ps[i][h]);
            pd[i][h] = fmaf(acc[ct][i], ad_v, pd[i][h]);
        }
    }
    #pragma unroll
    for (int o = 1; o < 16; o <<= 1) {
        #pragma unroll
        for (int i = 0; i < 4; ++i)
            #pragma unroll
            for (int h = 0; h < 4; ++h) {
                ps[i][h] += __shfl_xor(ps[i][h], o);
                pd[i][h] += __shfl_xor(pd[i][h], o);
            }
    }
    if (colg == 0) {
        #pragma unroll
        for (int i = 0; i < 4; ++i) {
            int m = m0 + w * 16 + kg * 4 + i;
            if (m < M) {
                #pragma unroll
                for (int h = 0; h < 4; ++h) {
                    a_s4[(size_t)m * 4 + h] = ps[i][h];
                    a_d4[(size_t)m * 4 + h] = pd[i][h];
                }
            }
        }
    }
}

// ---------------- MFMA GEMM layers 2/3 (bf16 A [M][K], bf16 WT [64][K]) + fused attn dots ----------------
template <int K, int NCATT>
__launch_bounds__(256)
__global__ void gemm_mfma_kernel(const ushortt* __restrict__ A, const ushortt* __restrict__ BT,
                                 ushortt* __restrict__ hB,
                                 const float* __restrict__ atts, const float* __restrict__ attd,
                                 float* __restrict__ a_s, float* __restrict__ a_d, int M) {
    __shared__ ushortt Abuf[64][40];
    __shared__ ushortt Bbuf[64][40];
    int m0 = blockIdx.x * 64;
    int t = threadIdx.x;
    int w = t >> 6, l = t & 63;
    int colg = l & 15, kg = l >> 4;
    int srow = t >> 2, sseg = t & 3;

    fx4 acc[4] = {};

    for (int k0 = 0; k0 < K; k0 += 32) {
        uint4 av = make_uint4(0u, 0u, 0u, 0u);
        if (m0 + srow < M)
            av = *(const uint4*)(A + (size_t)(m0 + srow) * K + k0 + sseg * 8);
        *(uint4*)&Abuf[srow][sseg * 8] = av;
        uint4 bv = *(const uint4*)(BT + (size_t)srow * K + k0 + sseg * 8);
        *(uint4*)&Bbuf[srow][sseg * 8] = bv;
        __syncthreads();
        bf16x8 a = *(const bf16x8*)&Abuf[w * 16 + colg][kg * 8];
        #pragma unroll
        for (int bt = 0; bt < 4; ++bt) {
            bf16x8 b = *(const bf16x8*)&Bbuf[bt * 16 + colg][kg * 8];
            acc[bt] = __builtin_amdgcn_mfma_f32_16x16x32_bf16(a, b, acc[bt], 0, 0, 0);
        }
        __syncthreads();
    }

    float ps[4] = {}, pd[4] = {};
    #pragma unroll
    for (int bt = 0; bt < 4; ++bt) {
        int cl = bt * 16 + colg;
        float as_v = (cl < NCATT) ? atts[cl] : 0.f;
        float ad_v = (cl < NCATT) ? attd[cl] : 0.f;
        #pragma unroll
        for (int i = 0; i < 4; ++i) {
            int m = m0 + w * 16 + kg * 4 + i;
            if (m < M)
                hB[(size_t)m * 64 + cl] = f2bf(acc[bt][i]);
            ps[i] = fmaf(acc[bt][i], as_v, ps[i]);
            pd[i] = fmaf(acc[bt][i], ad_v, pd[i]);
        }
    }
    #pragma unroll
    for (int o = 1; o < 16; o <<= 1) {
        #pragma unroll
        for (int i = 0; i < 4; ++i) {
            ps[i] += __shfl_xor(ps[i], o);
            pd[i] += __shfl_xor(pd[i], o);
        }
    }
    if (colg == 0) {
        #pragma unroll
        for (int i = 0; i < 4; ++i) {
            int m = m0 + w * 16 + kg * 4 + i;
            if (m < M) { a_s[m] = ps[i]; a_d[m] = pd[i]; }
        }
    }
}

// ---------------- alpha layer 1: edge-parallel, 4 heads -> alH[h*Etot + j] fp16 ----------------
__launch_bounds__(256)
__global__ void alpha4e_kernel(const int* __restrict__ csr, const int* __restrict__ dstv,
                               const float* __restrict__ a_s4, const float* __restrict__ a_d4,
                               __half* __restrict__ alH, int Etot) {
    int j = blockIdx.x * 256 + threadIdx.x;
    if (j >= Etot) return;
    int s = csr[j], d = dstv[j];
    fx4 as = *(const fx4*)&a_s4[(size_t)s * 4];
    fx4 ad = *(const fx4*)&a_d4[(size_t)d * 4];
    #pragma unroll
    for (int h = 0; h < 4; ++h) {
        float v = as[h] + ad[h];
        v = v > 0.f ? v : NEG_SLOPE * v;
        alH[(size_t)h * Etot + j] = __float2half(__expf(v));
    }
}

// ---------------- alpha single head: edge-parallel -> alE[j] fp16 ----------------
__launch_bounds__(256)
__global__ void alpha1e_kernel(const int* __restrict__ csr, const int* __restrict__ dstv,
                               const float* __restrict__ a_s, const float* __restrict__ a_d,
                               __half* __restrict__ alE, int Etot) {
    int j = blockIdx.x * 256 + threadIdx.x;
    if (j >= Etot) return;
    float v = a_s[csr[j]] + a_d[dstv[j]];
    v = v > 0.f ? v : NEG_SLOPE * v;
    alE[j] = __float2half(__expf(v));
}

// ---------------- PV layer 1: wave=node, 2 edges/step, 32 lanes/edge, unroll 4 ----------------
__launch_bounds__(256)
__global__ void pv1_kernel(const int* __restrict__ off, const int* __restrict__ csr,
                           const __half* __restrict__ alH, const ushortt* __restrict__ hB,
                           const float* __restrict__ bnsc, const float* __restrict__ bnsh,
                           ushortt* __restrict__ actb, int N, int Etot) {
    int node = blockIdx.x * 4 + (threadIdx.x >> 6);
    int lane = threadIdx.x & 63;
    if (node >= N) return;
    int half = lane >> 5, sub = lane & 31, head = sub >> 3;
    unsigned subb = (unsigned)(sub * 16);
    int beg = off[node], end = off[node + 1], deg = end - beg;
    const __half* alh = alH + (size_t)head * Etot;
    const char* hBb = (const char*)hB;
    float acc[8] = {};
    float ssum = 0.f;
    int nt = (deg + 1) >> 1;
    int j = beg + half;
    int t = 0;
    for (; t + 4 <= nt; t += 4, j += 8) {
        float av[4]; unsigned ro[4];
        #pragma unroll
        for (int q = 0; q < 4; ++q) {
            int jq = j + 2 * q;
            bool v = jq < end;
            int idx = v ? jq : beg;
            int s = csr[idx];
            av[q] = v ? __half2float(alh[idx]) : 0.f;
            ro[q] = (unsigned)s * 512u + subb;
        }
        uint4 h0 = *(const uint4*)(hBb + ro[0]);
        uint4 h1 = *(const uint4*)(hBb + ro[1]);
        uint4 h2 = *(const uint4*)(hBb + ro[2]);
        uint4 h3 = *(const uint4*)(hBb + ro[3]);
        acc8(acc, av[0], h0);
        acc8(acc, av[1], h1);
        acc8(acc, av[2], h2);
        acc8(acc, av[3], h3);
        ssum += (av[0] + av[1]) + (av[2] + av[3]);
    }
    for (; t < nt; ++t, j += 2) {
        bool v = j < end;
        int idx = v ? j : beg;
        int s = csr[idx];
        float a = v ? __half2float(alh[idx]) : 0.f;
        uint4 h = *(const uint4*)(hBb + (unsigned)s * 512u + subb);
        acc8(acc, a, h);
        ssum += a;
    }
    #pragma unroll
    for (int i = 0; i < 8; ++i) acc[i] += __shfl_xor(acc[i], 32);
    ssum += __shfl_xor(ssum, 32);
    if (half == 0) {
        float inv = 1.f / (ssum + 1e-16f);
        int g = sub * 8;
        float o[8];
        #pragma unroll
        for (int i = 0; i < 8; ++i) {
            float v = acc[i] * inv * bnsc[g + i] + bnsh[g + i];
            o[i] = v > 0.f ? v : expm1f(v);
        }
        uint4 pk = make_uint4(pack2bf(o[0], o[1]), pack2bf(o[2], o[3]),
                              pack2bf(o[4], o[5]), pack2bf(o[6], o[7]));
        *(uint4*)&actb[(size_t)node * 256 + g] = pk;
    }
}

// ---------------- PV layer 2: wave=node, 8 lanes/edge, streamed alpha; BN+ELU -> bf16 act2 ----------------
__launch_bounds__(256)
__global__ void pv2_kernel(const int* __restrict__ off, const int* __restrict__ csr,
                           const __half* __restrict__ alE, const ushortt* __restrict__ hB,
                           const float* __restrict__ bnsc, const float* __restrict__ bnsh,
                           ushortt* __restrict__ act2b, int N) {
    int node = blockIdx.x * 4 + (threadIdx.x >> 6);
    int lane = threadIdx.x & 63;
    if (node >= N) return;
    int grp = lane >> 3, sub = lane & 7;
    unsigned subb = (unsigned)(sub * 16);
    int beg = off[node], end = off[node + 1], deg = end - beg;
    const char* hBb = (const char*)hB;
    float acc[8] = {};
    float ssum = 0.f;
    int nt = (deg + 7) >> 3;
    int j = beg + grp;
    int t = 0;
    for (; t + 2 <= nt; t += 2, j += 16) {
        int jA = j, jB = j + 8;
        bool vA = jA < end, vB = jB < end;
        int iA = vA ? jA : beg, iB = vB ? jB : beg;
        int sA = csr[iA], sB = csr[iB];
        float aA = vA ? __half2float(alE[iA]) : 0.f;
        float aB = vB ? __half2float(alE[iB]) : 0.f;
        uint4 hA = *(const uint4*)(hBb + (unsigned)sA * 128u + subb);
        uint4 hBv = *(const uint4*)(hBb + (unsigned)sB * 128u + subb);
        acc8(acc, aA, hA);
        acc8(acc, aB, hBv);
        ssum += aA + aB;
    }
    for (; t < nt; ++t, j += 8) {
        bool v = j < end;
        int idx = v ? j : beg;
        int s = csr[idx];
        float a = v ? __half2float(alE[idx]) : 0.f;
        uint4 h = *(const uint4*)(hBb + (unsigned)s * 128u + subb);
        acc8(acc, a, h);
        ssum += a;
    }
    #pragma unroll
    for (int o = 8; o <= 32; o <<= 1) {
        #pragma unroll
        for (int i = 0; i < 8; ++i) acc[i] += __shfl_xor(acc[i], o);
        ssum += __shfl_xor(ssum, o);
    }
    if (lane < 8) {
        float inv = 1.f / (ssum + 1e-16f);
        int g = lane * 8;
        float o[8];
        #pragma unroll
        for (int i = 0; i < 8; ++i) {
            float v = acc[i] * inv * bnsc[256 + g + i] + bnsh[256 + g + i];
            o[i] = v > 0.f ? v : expm1f(v);
        }
        uint4 pk = make_uint4(pack2bf(o[0], o[1]), pack2bf(o[2], o[3]),
                              pack2bf(o[4], o[5]), pack2bf(o[6], o[7]));
        *(uint4*)&act2b[(size_t)node * 64 + g] = pk;
    }
}

// ---------------- PV layer 3: wave=node, streamed alpha; fused bias + log_softmax -> out ----------------
__launch_bounds__(256)
__global__ void pv3_kernel(const int* __restrict__ off, const int* __restrict__ csr,
                           const __half* __restrict__ alE, const ushortt* __restrict__ hB,
                           const float* __restrict__ bias, float* __restrict__ out, int N) {
    int node = blockIdx.x * 4 + (threadIdx.x >> 6);
    int lane = threadIdx.x & 63;
    if (node >= N) return;
    int grp = lane >> 3, sub = lane & 7;
    unsigned subb = (unsigned)(sub * 16);
    int beg = off[node], end = off[node + 1];
    const char* hBb = (const char*)hB;
    float acc[8] = {};
    float ssum = 0.f;
    for (int j0 = beg; j0 < end; j0 += 8) {
        int j = j0 + grp;
        bool v = j < end;
        int idx = v ? j : beg;
        int s = csr[idx];
        float a = v ? __half2float(alE[idx]) : 0.f;
        uint4 h = *(const uint4*)(hBb + (unsigned)s * 128u + subb);
        acc8(acc, a, h);
        ssum += a;
    }
    #pragma unroll
    for (int o = 8; o <= 32; o <<= 1) {
        #pragma unroll
        for (int i = 0; i < 8; ++i) acc[i] += __shfl_xor(acc[i], o);
        ssum += __shfl_xor(ssum, o);
    }
    float inv = 1.f / (ssum + 1e-16f);
    int g = lane * 8;
    bool act8 = lane < 5;
    float val[8];
    float mx = -INFINITY;
    #pragma unroll
    for (int i = 0; i < 8; ++i) {
        val[i] = act8 ? (acc[i] * inv + bias[act8 ? (g + i) : 0]) : -INFINITY;
        mx = fmaxf(mx, val[i]);
    }
    #pragma unroll
    for (int o = 1; o < 8; o <<= 1) mx = fmaxf(mx, __shfl_xor(mx, o));
    float se = 0.f;
    if (act8) {
        #pragma unroll
        for (int i = 0; i < 8; ++i) se += __expf(val[i] - mx);
    }
    #pragma unroll
    for (int o = 1; o < 8; o <<= 1) se += __shfl_xor(se, o);
    if (act8) {
        float lse = mx + logf(se);
        float* dst = &out[(size_t)node * 40 + g];
        fx4 v0 = {val[0] - lse, val[1] - lse, val[2] - lse, val[3] - lse};
        fx4 v1 = {val[4] - lse, val[5] - lse, val[6] - lse, val[7] - lse};
        *(fx4*)dst = v0;
        *(fx4*)(dst + 4) = v1;
    }
}

// ---------------- host ----------------
extern "C" void kernel_launch(void* const* d_in, const int* in_sizes, int n_in,
                              void* d_out, int out_size, void* d_ws, size_t ws_size,
                              hipStream_t stream) {
    const float* x      = (const float*)d_in[0];
    const int*   ei     = (const int*)d_in[1];
    const float* W1     = (const float*)d_in[2];
    const float* att_s1 = (const float*)d_in[3];
    const float* att_d1 = (const float*)d_in[4];
    const float* b1     = (const float*)d_in[5];
    const float* bn1g   = (const float*)d_in[6];
    const float* bn1b   = (const float*)d_in[7];
    const float* bn1m   = (const float*)d_in[8];
    const float* bn1v   = (const float*)d_in[9];
    const float* W2     = (const float*)d_in[10];
    const float* att_s2 = (const float*)d_in[11];
    const float* att_d2 = (const float*)d_in[12];
    const float* b2     = (const float*)d_in[13];
    const float* bn2g   = (const float*)d_in[14];
    const float* bn2b   = (const float*)d_in[15];
    const float* bn2m   = (const float*)d_in[16];
    const float* bn2v   = (const float*)d_in[17];
    const float* W3     = (const float*)d_in[18];
    const float* att_s3 = (const float*)d_in[19];
    const float* att_d3 = (const float*)d_in[20];
    const float* b3     = (const float*)d_in[21];

    const int N    = in_sizes[0] / IN_DIM;
    const int E    = in_sizes[1] / 2;
    const int Etot = E + N;

    int*   wsi = (int*)d_ws;
    float* wsf = (float*)d_ws;
    size_t p = 0;
    int*   off    = wsi + p; p += (size_t)N + 16;  p = (p + 3) & ~(size_t)3;
    int*   cursor = wsi + p; p += (size_t)N;       p = (p + 3) & ~(size_t)3;
    int*   flag   = wsi + p; p += 16;
    int*   csr    = wsi + p; p += (size_t)Etot;    p = (p + 3) & ~(size_t)3;
    int*   dstv   = wsi + p; p += (size_t)Etot;    p = (p + 3) & ~(size_t)3;
    float* a_s4   = wsf + p; p += (size_t)N * 4;
    float* a_d4   = wsf + p; p += (size_t)N * 4;
    float* bnsc   = wsf + p; p += 384;
    float* bnsh   = wsf + p; p += 384;
    size_t H = p;            p += (size_t)N * 128;   // hB1 (N*256 bf16) / hB23 (N*64 bf16)
    size_t A1 = p;           p += (size_t)N * 128;   // actb  (N*256 bf16)
    size_t A2 = p;           p += (size_t)N * 32;    // act2b (N*64 bf16)
    __half* alH = (__half*)(wsf + p); p += (size_t)Etot * 2 + 16;  // fp16 alpha (4 heads / reuse)
    ushortt* W1T = (ushortt*)(wsf + p); p += (256 * 128) / 2 + 16;
    ushortt* W2T = (ushortt*)(wsf + p); p += (64 * 256) / 2 + 16;
    ushortt* W3T = (ushortt*)(wsf + p); p += (64 * 64) / 2 + 16;
    if (ws_size < p * 4) return;

    ushortt* hB1   = (ushortt*)(wsf + H);
    ushortt* hB23  = (ushortt*)(wsf + H);
    ushortt* actb  = (ushortt*)(wsf + A1);
    ushortt* act2b = (ushortt*)(wsf + A2);
    __half*  alE   = alH;

    float* outp = (float*)d_out;

    // ---- CSR build + prep ----
    hipMemsetAsync(off, 0, ((size_t)N + 1) * sizeof(int), stream);
    detect_kernel<<<1, 256, 0, stream>>>((const unsigned int*)ei, flag);
    {
        int blocks = (Etot + 255) / 256;
        hist_kernel<<<blocks, 256, 0, stream>>>(ei, flag, off, E, Etot);
        scan_kernel<<<1, 1024, 0, stream>>>(off, cursor, N + 1);
        fill_dstv_kernel<<<(N + 3) / 4, 256, 0, stream>>>(off, dstv, N);
        scatter_kernel<<<blocks, 256, 0, stream>>>(ei, flag, cursor, csr, E, Etot);
    }
    {
        int total = 320 + 256 * 128 + 64 * 256 + 64 * 64;
        prep_all_kernel<<<(total + 255) / 256, 256, 0, stream>>>(
            b1, bn1g, bn1b, bn1m, bn1v, b2, bn2g, bn2b, bn2m, bn2v,
            W1, W2, W3, bnsc, bnsh, W1T, W2T, W3T);
    }

    const int gm64 = (N + 63) / 64;
    const int nb4 = (N + 3) / 4;
    const int eb = (Etot + 255) / 256;

    // ---- layer 1 ----
    gemm1_mfma_kernel<<<gm64, 256, 0, stream>>>(x, W1T, hB1, att_s1, att_d1, a_s4, a_d4, N);
    alpha4e_kernel<<<eb, 256, 0, stream>>>(csr, dstv, a_s4, a_d4, alH, Etot);
    pv1_kernel<<<nb4, 256, 0, stream>>>(off, csr, alH, hB1, bnsc, bnsh, actb, N, Etot);

    // ---- layer 2 ----
    gemm_mfma_kernel<256, 64><<<gm64, 256, 0, stream>>>(actb, W2T, hB23, att_s2, att_d2,
                                                        a_s4, a_d4, N);
    alpha1e_kernel<<<eb, 256, 0, stream>>>(csr, dstv, a_s4, a_d4, alE, Etot);
    pv2_kernel<<<nb4, 256, 0, stream>>>(off, csr, alE, hB23, bnsc, bnsh, act2b, N);

    // ---- layer 3 (log_softmax fused into PV epilogue) ----
    gemm_mfma_kernel<64, 40><<<gm64, 256, 0, stream>>>(act2b, W3T, hB23, att_s3, att_d3,
                                                       a_s4, a_d4, N);
    alpha1e_kernel<<<eb, 256, 0, stream>>>(csr, dstv, a_s4, a_d4, alE, Etot);
    pv3_kernel<<<nb4, 256, 0, stream>>>(off, csr, alE, hB23, b3, outp, N);
}

// Round 17
// 655.887 us; speedup vs baseline: 1.3991x; 1.0185x over previous
//
#include <hip/hip_runtime.h>
#include <hip/hip_fp16.h>
#include <cstdint>

#define IN_DIM   128
#define HIDC     64
#define HEADS    4
#define OUT_DIM  40
#define NEG_SLOPE 0.2f
#define BN_EPS   1e-5f

typedef unsigned short ushortt;
typedef float fx4 __attribute__((ext_vector_type(4)));
typedef short bf16x8 __attribute__((ext_vector_type(8)));

__device__ __forceinline__ float bfval(ushortt u) {
    return __uint_as_float(((unsigned)u) << 16);
}
__device__ __forceinline__ ushortt f2bf(float f) {
    unsigned u = __float_as_uint(f);
    u += 0x7fffu + ((u >> 16) & 1u);
    return (ushortt)(u >> 16);
}
__device__ __forceinline__ unsigned pack2bf(float a, float b) {
    return (unsigned)f2bf(a) | ((unsigned)f2bf(b) << 16);
}

// acc[0..7] += a * bf16x8(h)
__device__ __forceinline__ void acc8(float* acc, float a, uint4 h) {
    unsigned u;
    u = h.x;
    acc[0] = fmaf(a, __uint_as_float(u << 16), acc[0]);
    acc[1] = fmaf(a, __uint_as_float(u & 0xffff0000u), acc[1]);
    u = h.y;
    acc[2] = fmaf(a, __uint_as_float(u << 16), acc[2]);
    acc[3] = fmaf(a, __uint_as_float(u & 0xffff0000u), acc[3]);
    u = h.z;
    acc[4] = fmaf(a, __uint_as_float(u << 16), acc[4]);
    acc[5] = fmaf(a, __uint_as_float(u & 0xffff0000u), acc[5]);
    u = h.w;
    acc[6] = fmaf(a, __uint_as_float(u << 16), acc[6]);
    acc[7] = fmaf(a, __uint_as_float(u & 0xffff0000u), acc[7]);
}

// ---------------- CSR build ----------------
__global__ void detect_kernel(const unsigned int* __restrict__ e, int* __restrict__ flag) {
    __shared__ int any;
    if (threadIdx.x == 0) any = 0;
    __syncthreads();
    for (int i = threadIdx.x; i < 1024; i += 256)
        if (e[2 * i + 1] != 0u) any = 1;
    __syncthreads();
    if (threadIdx.x == 0) flag[0] = any ? 0 : 1;   // 1 => int64
}

__device__ __forceinline__ int load_idx(const int* ei, int is64, long long pos) {
    return is64 ? ei[2 * pos] : ei[pos];
}

__global__ void hist_kernel(const int* __restrict__ ei, const int* __restrict__ flag,
                            int* __restrict__ deg, int E, int Etot) {
    int i = blockIdx.x * 256 + threadIdx.x;
    if (i >= Etot) return;
    int is64 = flag[0];
    int dst = (i < E) ? load_idx(ei, is64, (long long)E + i) : (i - E);
    atomicAdd(&deg[dst], 1);
}

// exclusive scan in place (single block, 1024 thr, 4 elems/thr); mirrors into cursor[i], i<n-1
__global__ void scan_kernel(int* __restrict__ data, int* __restrict__ cursor, int n) {
    __shared__ int wsum[16];
    __shared__ int chunk_total;
    int lane = threadIdx.x & 63;
    int w = threadIdx.x >> 6;
    int carry = 0;
    for (int base = 0; base < n; base += 4096) {
        int i4 = base + (int)threadIdx.x * 4;
        int d0 = 0, d1 = 0, d2 = 0, d3 = 0;
        if (i4 + 3 < n) {
            int4 v = *(const int4*)&data[i4];
            d0 = v.x; d1 = v.y; d2 = v.z; d3 = v.w;
        } else {
            if (i4 + 0 < n) d0 = data[i4 + 0];
            if (i4 + 1 < n) d1 = data[i4 + 1];
            if (i4 + 2 < n) d2 = data[i4 + 2];
            if (i4 + 3 < n) d3 = data[i4 + 3];
        }
        int tsum = d0 + d1 + d2 + d3;
        int x = tsum;
        #pragma unroll
        for (int ofs = 1; ofs < 64; ofs <<= 1) {
            int y = __shfl_up(x, ofs);
            if (lane >= ofs) x += y;
        }
        if (lane == 63) wsum[w] = x;
        __syncthreads();
        if (w == 0) {
            int s = (lane < 16) ? wsum[lane] : 0;
            #pragma unroll
            for (int ofs = 1; ofs < 16; ofs <<= 1) {
                int y = __shfl_up(s, ofs);
                if (lane >= ofs) s += y;
            }
            if (lane < 16) wsum[lane] = s;
            if (lane == 15) chunk_total = s;
        }
        __syncthreads();
        int woff = (w > 0) ? wsum[w - 1] : 0;
        int e0 = (x - tsum) + woff + carry;
        int e1 = e0 + d0, e2 = e1 + d1, e3 = e2 + d2;
        if (i4 + 3 < n) {
            *(int4*)&data[i4] = make_int4(e0, e1, e2, e3);
        } else {
            if (i4 + 0 < n) data[i4 + 0] = e0;
            if (i4 + 1 < n) data[i4 + 1] = e1;
            if (i4 + 2 < n) data[i4 + 2] = e2;
            if (i4 + 3 < n) data[i4 + 3] = e3;
        }
        if (i4 + 0 < n - 1) cursor[i4 + 0] = e0;
        if (i4 + 1 < n - 1) cursor[i4 + 1] = e1;
        if (i4 + 2 < n - 1) cursor[i4 + 2] = e2;
        if (i4 + 3 < n - 1) cursor[i4 + 3] = e3;
        int ct = chunk_total;
        __syncthreads();
        carry += ct;
    }
}

// dstv[j] = node for j in [off[node], off[node+1]) — sequential coalesced writes
__global__ void fill_dstv_kernel(const int* __restrict__ off, int* __restrict__ dstv, int N) {
    int node = blockIdx.x * 4 + (threadIdx.x >> 6);
    int lane = threadIdx.x & 63;
    if (node >= N) return;
    int beg = off[node], end = off[node + 1];
    for (int j = beg + lane; j < end; j += 64) dstv[j] = node;
}

__global__ void scatter_kernel(const int* __restrict__ ei, const int* __restrict__ flag,
                               int* __restrict__ cursor, int* __restrict__ csr,
                               int E, int Etot) {
    int i = blockIdx.x * 256 + threadIdx.x;
    if (i >= Etot) return;
    int is64 = flag[0];
    int src, dst;
    if (i < E) {
        src = load_idx(ei, is64, i);
        dst = load_idx(ei, is64, (long long)E + i);
    } else {
        src = dst = i - E;
    }
    int pos = atomicAdd(&cursor[dst], 1);
    csr[pos] = src;
}

// ---------------- one-shot prep: BN fold + three weight transposes (bf16) ----------------
__global__ void prep_all_kernel(const float* b1, const float* g1, const float* bb1,
                                const float* m1, const float* v1,
                                const float* b2, const float* g2, const float* bb2,
                                const float* m2, const float* v2,
                                const float* W1, const float* W2, const float* W3,
                                float* __restrict__ bnsc, float* __restrict__ bnsh,
                                ushortt* __restrict__ W1T, ushortt* __restrict__ W2T,
                                ushortt* __restrict__ W3T) {
    int i = blockIdx.x * 256 + threadIdx.x;
    if (i < 320) {
        if (i < 256) {
            float s = g1[i] * rsqrtf(v1[i] + BN_EPS);
            bnsc[i] = s;
            bnsh[i] = (b1[i] - m1[i]) * s + bb1[i];
        } else {
            int c = i - 256;
            float s = g2[c] * rsqrtf(v2[c] + BN_EPS);
            bnsc[i] = s;
            bnsh[i] = (b2[c] - m2[c]) * s + bb2[c];
        }
        return;
    }
    int j = i - 320;
    if (j < 256 * 128) {                       // W1T[n][k]
        int n = j >> 7, k = j & 127;
        W1T[j] = f2bf(W1[(size_t)k * 256 + n]);
        return;
    }
    j -= 256 * 128;
    if (j < 64 * 256) {                        // W2T[n][k]
        int n = j >> 8, k = j & 255;
        W2T[j] = f2bf(W2[(size_t)k * 64 + n]);
        return;
    }
    j -= 64 * 256;
    if (j < 64 * 64) {                         // W3T[n][k] (pad rows >= 40 zero)
        int n = j >> 6, k = j & 63;
        W3T[j] = (n < OUT_DIM) ? f2bf(W3[(size_t)k * OUT_DIM + n]) : (ushortt)0;
    }
}

// ---------------- MFMA GEMM layer 1: fp32 A [M][128] x W1T bf16 [256][128], 64x256 tile ----------------
__launch_bounds__(256)
__global__ void gemm1_mfma_kernel(const float* __restrict__ x, const ushortt* __restrict__ BT,
                                  ushortt* __restrict__ hB,
                                  const float* __restrict__ atts, const float* __restrict__ attd,
                                  float* __restrict__ a_s4, float* __restrict__ a_d4, int M) {
    __shared__ ushortt Abuf[64][40];
    __shared__ ushortt Bbuf[256][40];
    int m0 = blockIdx.x * 64;
    int t = threadIdx.x;
    int w = t >> 6, l = t & 63;
    int colg = l & 15, kg = l >> 4;
    int srow = t >> 2, sseg = t & 3;

    fx4 acc[16] = {};

    for (int k0 = 0; k0 < 128; k0 += 32) {
        float4 v0 = make_float4(0.f, 0.f, 0.f, 0.f), v1 = v0;
        if (m0 + srow < M) {
            const float4* sp = (const float4*)(x + (size_t)(m0 + srow) * 128 + k0 + sseg * 8);
            v0 = sp[0]; v1 = sp[1];
        }
        *(uint4*)&Abuf[srow][sseg * 8] = make_uint4(pack2bf(v0.x, v0.y), pack2bf(v0.z, v0.w),
                                                    pack2bf(v1.x, v1.y), pack2bf(v1.z, v1.w));
        #pragma unroll
        for (int seg = 0; seg < 4; ++seg)
            *(uint4*)&Bbuf[t][seg * 8] = *(const uint4*)(BT + (size_t)t * 128 + k0 + seg * 8);
        __syncthreads();
        bf16x8 a = *(const bf16x8*)&Abuf[w * 16 + colg][kg * 8];
        #pragma unroll
        for (int ct = 0; ct < 16; ++ct) {
            bf16x8 b = *(const bf16x8*)&Bbuf[ct * 16 + colg][kg * 8];
            acc[ct] = __builtin_amdgcn_mfma_f32_16x16x32_bf16(a, b, acc[ct], 0, 0, 0);
        }
        __syncthreads();
    }

    float ps[4][4] = {}, pd[4][4] = {};
    #pragma unroll
    for (int ct = 0; ct < 16; ++ct) {
        int cl = ct * 16 + colg;
        int h = cl >> 6;
        float as_v = atts[cl], ad_v = attd[cl];
        #pragma unroll
        for (int i = 0; i < 4; ++i) {
            int m = m0 + w * 16 + kg * 4 + i;
            if (m < M)
                hB[(size_t)m * 256 + cl] = f2bf(acc[ct][i]);
            ps[i][h] = fmaf(acc[ct][i], as_v, ps[i][h]);
            pd[i][h] = fmaf(acc[ct][i], ad_v, pd[i][h]);
        }
    }
    #pragma unroll
    for (int o = 1; o < 16; o <<= 1) {
        #pragma unroll
        for (int i = 0; i < 4; ++i)
            #pragma unroll
            for (int h = 0; h < 4; ++h) {
                ps[i][h] += __shfl_xor(ps[i][h], o);
                pd[i][h] += __shfl_xor(pd[i][h], o);
            }
    }
    if (colg == 0) {
        #pragma unroll
        for (int i = 0; i < 4; ++i) {
            int m = m0 + w * 16 + kg * 4 + i;
            if (m < M) {
                #pragma unroll
                for (int h = 0; h < 4; ++h) {
                    a_s4[(size_t)m * 4 + h] = ps[i][h];
                    a_d4[(size_t)m * 4 + h] = pd[i][h];
                }
            }
        }
    }
}

// ---------------- MFMA GEMM layers 2/3 (bf16 A [M][K], bf16 WT [64][K]) + fused attn dots ----------------
template <int K, int NCATT>
__launch_bounds__(256)
__global__ void gemm_mfma_kernel(const ushortt* __restrict__ A, const ushortt* __restrict__ BT,
                                 ushortt* __restrict__ hB,
                                 const float* __restrict__ atts, const float* __restrict__ attd,
                                 float* __restrict__ a_s, float* __restrict__ a_d, int M) {
    __shared__ ushortt Abuf[64][40];
    __shared__ ushortt Bbuf[64][40];
    int m0 = blockIdx.x * 64;
    int t = threadIdx.x;
    int w = t >> 6, l = t & 63;
    int colg = l & 15, kg = l >> 4;
    int srow = t >> 2, sseg = t & 3;

    fx4 acc[4] = {};

    for (int k0 = 0; k0 < K; k0 += 32) {
        uint4 av = make_uint4(0u, 0u, 0u, 0u);
        if (m0 + srow < M)
            av = *(const uint4*)(A + (size_t)(m0 + srow) * K + k0 + sseg * 8);
        *(uint4*)&Abuf[srow][sseg * 8] = av;
        uint4 bv = *(const uint4*)(BT + (size_t)srow * K + k0 + sseg * 8);
        *(uint4*)&Bbuf[srow][sseg * 8] = bv;
        __syncthreads();
        bf16x8 a = *(const bf16x8*)&Abuf[w * 16 + colg][kg * 8];
        #pragma unroll
        for (int bt = 0; bt < 4; ++bt) {
            bf16x8 b = *(const bf16x8*)&Bbuf[bt * 16 + colg][kg * 8];
            acc[bt] = __builtin_amdgcn_mfma_f32_16x16x32_bf16(a, b, acc[bt], 0, 0, 0);
        }
        __syncthreads();
    }

    float ps[4] = {}, pd[4] = {};
    #pragma unroll
    for (int bt = 0; bt < 4; ++bt) {
        int cl = bt * 16 + colg;
        float as_v = (cl < NCATT) ? atts[cl] : 0.f;
        float ad_v = (cl < NCATT) ? attd[cl] : 0.f;
        #pragma unroll
        for (int i = 0; i < 4; ++i) {
            int m = m0 + w * 16 + kg * 4 + i;
            if (m < M)
                hB[(size_t)m * 64 + cl] = f2bf(acc[bt][i]);
            ps[i] = fmaf(acc[bt][i], as_v, ps[i]);
            pd[i] = fmaf(acc[bt][i], ad_v, pd[i]);
        }
    }
    #pragma unroll
    for (int o = 1; o < 16; o <<= 1) {
        #pragma unroll
        for (int i = 0; i < 4; ++i) {
            ps[i] += __shfl_xor(ps[i], o);
            pd[i] += __shfl_xor(pd[i], o);
        }
    }
    if (colg == 0) {
        #pragma unroll
        for (int i = 0; i < 4; ++i) {
            int m = m0 + w * 16 + kg * 4 + i;
            if (m < M) { a_s[m] = ps[i]; a_d[m] = pd[i]; }
        }
    }
}

// ---------------- alpha layer 1: edge-parallel, 4 heads -> alH[h*Etot + j] fp16 ----------------
__launch_bounds__(256)
__global__ void alpha4e_kernel(const int* __restrict__ csr, const int* __restrict__ dstv,
                               const float* __restrict__ a_s4, const float* __restrict__ a_d4,
                               __half* __restrict__ alH, int Etot) {
    int j = blockIdx.x * 256 + threadIdx.x;
    if (j >= Etot) return;
    int s = csr[j], d = dstv[j];
    fx4 as = *(const fx4*)&a_s4[(size_t)s * 4];
    fx4 ad = *(const fx4*)&a_d4[(size_t)d * 4];
    #pragma unroll
    for (int h = 0; h < 4; ++h) {
        float v = as[h] + ad[h];
        v = v > 0.f ? v : NEG_SLOPE * v;
        alH[(size_t)h * Etot + j] = __float2half(__expf(v));
    }
}

// ---------------- PV layer 1: wave=node, 2 edges/step, 32 lanes/edge, unroll 4 ----------------
__launch_bounds__(256)
__global__ void pv1_kernel(const int* __restrict__ off, const int* __restrict__ csr,
                           const __half* __restrict__ alH, const ushortt* __restrict__ hB,
                           const float* __restrict__ bnsc, const float* __restrict__ bnsh,
                           ushortt* __restrict__ actb, int N, int Etot) {
    int node = blockIdx.x * 4 + (threadIdx.x >> 6);
    int lane = threadIdx.x & 63;
    if (node >= N) return;
    int half = lane >> 5, sub = lane & 31, head = sub >> 3;
    unsigned subb = (unsigned)(sub * 16);
    int beg = off[node], end = off[node + 1], deg = end - beg;
    const __half* alh = alH + (size_t)head * Etot;
    const char* hBb = (const char*)hB;
    float acc[8] = {};
    float ssum = 0.f;
    int nt = (deg + 1) >> 1;
    int j = beg + half;
    int t = 0;
    for (; t + 4 <= nt; t += 4, j += 8) {
        float av[4]; unsigned ro[4];
        #pragma unroll
        for (int q = 0; q < 4; ++q) {
            int jq = j + 2 * q;
            bool v = jq < end;
            int idx = v ? jq : beg;
            int s = csr[idx];
            av[q] = v ? __half2float(alh[idx]) : 0.f;
            ro[q] = (unsigned)s * 512u + subb;
        }
        uint4 h0 = *(const uint4*)(hBb + ro[0]);
        uint4 h1 = *(const uint4*)(hBb + ro[1]);
        uint4 h2 = *(const uint4*)(hBb + ro[2]);
        uint4 h3 = *(const uint4*)(hBb + ro[3]);
        acc8(acc, av[0], h0);
        acc8(acc, av[1], h1);
        acc8(acc, av[2], h2);
        acc8(acc, av[3], h3);
        ssum += (av[0] + av[1]) + (av[2] + av[3]);
    }
    for (; t < nt; ++t, j += 2) {
        bool v = j < end;
        int idx = v ? j : beg;
        int s = csr[idx];
        float a = v ? __half2float(alh[idx]) : 0.f;
        uint4 h = *(const uint4*)(hBb + (unsigned)s * 512u + subb);
        acc8(acc, a, h);
        ssum += a;
    }
    #pragma unroll
    for (int i = 0; i < 8; ++i) acc[i] += __shfl_xor(acc[i], 32);
    ssum += __shfl_xor(ssum, 32);
    if (half == 0) {
        float inv = 1.f / (ssum + 1e-16f);
        int g = sub * 8;
        float o[8];
        #pragma unroll
        for (int i = 0; i < 8; ++i) {
            float v = acc[i] * inv * bnsc[g + i] + bnsh[g + i];
            o[i] = v > 0.f ? v : expm1f(v);
        }
        uint4 pk = make_uint4(pack2bf(o[0], o[1]), pack2bf(o[2], o[3]),
                              pack2bf(o[4], o[5]), pack2bf(o[6], o[7]));
        *(uint4*)&actb[(size_t)node * 256 + g] = pk;
    }
}

// ---------------- PV layer 2: wave=node, 8 lanes/edge, INLINE alpha; BN+ELU -> bf16 act2 ----------------
__launch_bounds__(256)
__global__ void pv2_kernel(const int* __restrict__ off, const int* __restrict__ csr,
                           const float* __restrict__ a_s, const float* __restrict__ a_d,
                           const ushortt* __restrict__ hB,
                           const float* __restrict__ bnsc, const float* __restrict__ bnsh,
                           ushortt* __restrict__ act2b, int N) {
    int node = blockIdx.x * 4 + (threadIdx.x >> 6);
    int lane = threadIdx.x & 63;
    if (node >= N) return;
    int grp = lane >> 3, sub = lane & 7;
    unsigned subb = (unsigned)(sub * 16);
    int beg = off[node], end = off[node + 1], deg = end - beg;
    float ad = a_d[node];
    const char* hBb = (const char*)hB;
    float acc[8] = {};
    float ssum = 0.f;
    int nt = (deg + 7) >> 3;
    int j = beg + grp;
    int t = 0;
    for (; t + 2 <= nt; t += 2, j += 16) {
        int jA = j, jB = j + 8;
        bool vA = jA < end, vB = jB < end;
        int iA = vA ? jA : beg, iB = vB ? jB : beg;
        int sA = csr[iA], sB = csr[iB];
        float wA = a_s[sA] + ad; wA = wA > 0.f ? wA : NEG_SLOPE * wA;
        float wB = a_s[sB] + ad; wB = wB > 0.f ? wB : NEG_SLOPE * wB;
        float aA = vA ? __expf(wA) : 0.f;
        float aB = vB ? __expf(wB) : 0.f;
        uint4 hA = *(const uint4*)(hBb + (unsigned)sA * 128u + subb);
        uint4 hBv = *(const uint4*)(hBb + (unsigned)sB * 128u + subb);
        acc8(acc, aA, hA);
        acc8(acc, aB, hBv);
        ssum += aA + aB;
    }
    for (; t < nt; ++t, j += 8) {
        bool v = j < end;
        int idx = v ? j : beg;
        int s = csr[idx];
        float w = a_s[s] + ad; w = w > 0.f ? w : NEG_SLOPE * w;
        float a = v ? __expf(w) : 0.f;
        uint4 h = *(const uint4*)(hBb + (unsigned)s * 128u + subb);
        acc8(acc, a, h);
        ssum += a;
    }
    #pragma unroll
    for (int o = 8; o <= 32; o <<= 1) {
        #pragma unroll
        for (int i = 0; i < 8; ++i) acc[i] += __shfl_xor(acc[i], o);
        ssum += __shfl_xor(ssum, o);
    }
    if (lane < 8) {
        float inv = 1.f / (ssum + 1e-16f);
        int g = lane * 8;
        float o[8];
        #pragma unroll
        for (int i = 0; i < 8; ++i) {
            float v = acc[i] * inv * bnsc[256 + g + i] + bnsh[256 + g + i];
            o[i] = v > 0.f ? v : expm1f(v);
        }
        uint4 pk = make_uint4(pack2bf(o[0], o[1]), pack2bf(o[2], o[3]),
                              pack2bf(o[4], o[5]), pack2bf(o[6], o[7]));
        *(uint4*)&act2b[(size_t)node * 64 + g] = pk;
    }
}

// ---------------- PV layer 3: wave=node, INLINE alpha; fused bias + log_softmax -> out ----------------
__launch_bounds__(256)
__global__ void pv3_kernel(const int* __restrict__ off, const int* __restrict__ csr,
                           const float* __restrict__ a_s, const float* __restrict__ a_d,
                           const ushortt* __restrict__ hB, const float* __restrict__ bias,
                           float* __restrict__ out, int N) {
    int node = blockIdx.x * 4 + (threadIdx.x >> 6);
    int lane = threadIdx.x & 63;
    if (node >= N) return;
    int grp = lane >> 3, sub = lane & 7;
    unsigned subb = (unsigned)(sub * 16);
    int beg = off[node], end = off[node + 1];
    float ad = a_d[node];
    const char* hBb = (const char*)hB;
    float acc[8] = {};
    float ssum = 0.f;
    for (int j0 = beg; j0 < end; j0 += 8) {
        int j = j0 + grp;
        bool v = j < end;
        int idx = v ? j : beg;
        int s = csr[idx];
        float w = a_s[s] + ad; w = w > 0.f ? w : NEG_SLOPE * w;
        float a = v ? __expf(w) : 0.f;
        uint4 h = *(const uint4*)(hBb + (unsigned)s * 128u + subb);
        acc8(acc, a, h);
        ssum += a;
    }
    #pragma unroll
    for (int o = 8; o <= 32; o <<= 1) {
        #pragma unroll
        for (int i = 0; i < 8; ++i) acc[i] += __shfl_xor(acc[i], o);
        ssum += __shfl_xor(ssum, o);
    }
    float inv = 1.f / (ssum + 1e-16f);
    int g = lane * 8;
    bool act8 = lane < 5;
    float val[8];
    float mx = -INFINITY;
    #pragma unroll
    for (int i = 0; i < 8; ++i) {
        val[i] = act8 ? (acc[i] * inv + bias[act8 ? (g + i) : 0]) : -INFINITY;
        mx = fmaxf(mx, val[i]);
    }
    #pragma unroll
    for (int o = 1; o < 8; o <<= 1) mx = fmaxf(mx, __shfl_xor(mx, o));
    float se = 0.f;
    if (act8) {
        #pragma unroll
        for (int i = 0; i < 8; ++i) se += __expf(val[i] - mx);
    }
    #pragma unroll
    for (int o = 1; o < 8; o <<= 1) se += __shfl_xor(se, o);
    if (act8) {
        float lse = mx + logf(se);
        float* dst = &out[(size_t)node * 40 + g];
        fx4 v0 = {val[0] - lse, val[1] - lse, val[2] - lse, val[3] - lse};
        fx4 v1 = {val[4] - lse, val[5] - lse, val[6] - lse, val[7] - lse};
        *(fx4*)dst = v0;
        *(fx4*)(dst + 4) = v1;
    }
}

// ---------------- host ----------------
extern "C" void kernel_launch(void* const* d_in, const int* in_sizes, int n_in,
                              void* d_out, int out_size, void* d_ws, size_t ws_size,
                              hipStream_t stream) {
    const float* x      = (const float*)d_in[0];
    const int*   ei     = (const int*)d_in[1];
    const float* W1     = (const float*)d_in[2];
    const float* att_s1 = (const float*)d_in[3];
    const float* att_d1 = (const float*)d_in[4];
    const float* b1     = (const float*)d_in[5];
    const float* bn1g   = (const float*)d_in[6];
    const float* bn1b   = (const float*)d_in[7];
    const float* bn1m   = (const float*)d_in[8];
    const float* bn1v   = (const float*)d_in[9];
    const float* W2     = (const float*)d_in[10];
    const float* att_s2 = (const float*)d_in[11];
    const float* att_d2 = (const float*)d_in[12];
    const float* b2     = (const float*)d_in[13];
    const float* bn2g   = (const float*)d_in[14];
    const float* bn2b   = (const float*)d_in[15];
    const float* bn2m   = (const float*)d_in[16];
    const float* bn2v   = (const float*)d_in[17];
    const float* W3     = (const float*)d_in[18];
    const float* att_s3 = (const float*)d_in[19];
    const float* att_d3 = (const float*)d_in[20];
    const float* b3     = (const float*)d_in[21];

    const int N    = in_sizes[0] / IN_DIM;
    const int E    = in_sizes[1] / 2;
    const int Etot = E + N;

    int*   wsi = (int*)d_ws;
    float* wsf = (float*)d_ws;
    size_t p = 0;
    int*   off    = wsi + p; p += (size_t)N + 16;  p = (p + 3) & ~(size_t)3;
    int*   cursor = wsi + p; p += (size_t)N;       p = (p + 3) & ~(size_t)3;
    int*   flag   = wsi + p; p += 16;
    int*   csr    = wsi + p; p += (size_t)Etot;    p = (p + 3) & ~(size_t)3;
    int*   dstv   = wsi + p; p += (size_t)Etot;    p = (p + 3) & ~(size_t)3;
    float* a_s4   = wsf + p; p += (size_t)N * 4;
    float* a_d4   = wsf + p; p += (size_t)N * 4;
    float* bnsc   = wsf + p; p += 384;
    float* bnsh   = wsf + p; p += 384;
    size_t H = p;            p += (size_t)N * 128;   // hB1 (N*256 bf16) / hB23 (N*64 bf16)
    size_t A1 = p;           p += (size_t)N * 128;   // actb  (N*256 bf16)
    size_t A2 = p;           p += (size_t)N * 32;    // act2b (N*64 bf16)
    __half* alH = (__half*)(wsf + p); p += (size_t)Etot * 2 + 16;  // fp16 alpha (layer 1)
    ushortt* W1T = (ushortt*)(wsf + p); p += (256 * 128) / 2 + 16;
    ushortt* W2T = (ushortt*)(wsf + p); p += (64 * 256) / 2 + 16;
    ushortt* W3T = (ushortt*)(wsf + p); p += (64 * 64) / 2 + 16;
    if (ws_size < p * 4) return;

    ushortt* hB1   = (ushortt*)(wsf + H);
    ushortt* hB23  = (ushortt*)(wsf + H);
    ushortt* actb  = (ushortt*)(wsf + A1);
    ushortt* act2b = (ushortt*)(wsf + A2);

    float* outp = (float*)d_out;

    // ---- CSR build + prep ----
    hipMemsetAsync(off, 0, ((size_t)N + 1) * sizeof(int), stream);
    detect_kernel<<<1, 256, 0, stream>>>((const unsigned int*)ei, flag);
    {
        int blocks = (Etot + 255) / 256;
        hist_kernel<<<blocks, 256, 0, stream>>>(ei, flag, off, E, Etot);
        scan_kernel<<<1, 1024, 0, stream>>>(off, cursor, N + 1);
        fill_dstv_kernel<<<(N + 3) / 4, 256, 0, stream>>>(off, dstv, N);
        scatter_kernel<<<blocks, 256, 0, stream>>>(ei, flag, cursor, csr, E, Etot);
    }
    {
        int total = 320 + 256 * 128 + 64 * 256 + 64 * 64;
        prep_all_kernel<<<(total + 255) / 256, 256, 0, stream>>>(
            b1, bn1g, bn1b, bn1m, bn1v, b2, bn2g, bn2b, bn2m, bn2v,
            W1, W2, W3, bnsc, bnsh, W1T, W2T, W3T);
    }

    const int gm64 = (N + 63) / 64;
    const int nb4 = (N + 3) / 4;
    const int eb = (Etot + 255) / 256;

    // ---- layer 1 ----
    gemm1_mfma_kernel<<<gm64, 256, 0, stream>>>(x, W1T, hB1, att_s1, att_d1, a_s4, a_d4, N);
    alpha4e_kernel<<<eb, 256, 0, stream>>>(csr, dstv, a_s4, a_d4, alH, Etot);
    pv1_kernel<<<nb4, 256, 0, stream>>>(off, csr, alH, hB1, bnsc, bnsh, actb, N, Etot);

    // ---- layer 2 (alpha inlined in PV) ----
    gemm_mfma_kernel<256, 64><<<gm64, 256, 0, stream>>>(actb, W2T, hB23, att_s2, att_d2,
                                                        a_s4, a_d4, N);
    pv2_kernel<<<nb4, 256, 0, stream>>>(off, csr, a_s4, a_d4, hB23, bnsc, bnsh, act2b, N);

    // ---- layer 3 (alpha inlined; log_softmax fused into PV epilogue) ----
    gemm_mfma_kernel<64, 40><<<gm64, 256, 0, stream>>>(act2b, W3T, hB23, att_s3, att_d3,
                                                       a_s4, a_d4, N);
    pv3_kernel<<<nb4, 256, 0, stream>>>(off, csr, a_s4, a_d4, hB23, b3, outp, N);
}